// Round 7
// baseline (195.801 us; speedup 1.0000x reference)
//
#include <hip/hip_runtime.h>
#include <stdint.h>

// Problem: B=16, C=64, H=W=128. fp32 in/out.
#define NB   16
#define NCH  64
#define HH   128
#define NPOS (HH*HH)        // 16384 spatial positions

typedef short bf16x8 __attribute__((ext_vector_type(8)));   // 8 bf16 = 4 VGPRs
typedef float f32x4  __attribute__((ext_vector_type(4)));

__device__ __forceinline__ unsigned short f2bf(float f){
  unsigned int u = __float_as_uint(f);
  u += 0x7FFFu + ((u>>16)&1u);          // RNE; inputs finite
  return (unsigned short)(u>>16);
}
__device__ __forceinline__ unsigned int pk2(float a, float b){
  return (unsigned int)f2bf(a) | ((unsigned int)f2bf(b)<<16);
}
__device__ __forceinline__ bf16x8 pk8(float4 a, float4 b){
  union { bf16x8 v; unsigned int u[4]; } r;
  r.u[0] = pk2(a.x, a.y); r.u[1] = pk2(a.z, a.w);
  r.u[2] = pk2(b.x, b.y); r.u[3] = pk2(b.z, b.w);
  return r.v;
}

// XOR swizzle on byte bits 4-6: spreads 16 consecutive rows over 8 16B slots.
__device__ __forceinline__ int swz(int row, int cb){
  return cb ^ (((row & 7) ^ ((row >> 3) & 7)) << 4);
}

// ---------------- Kernel 1: Q/V (m=0, from x) and K (m=1, from att) -------
// (unchanged from round 5/6 — verified fast)
__global__ __launch_bounds__(256, 6) void rc_conv_in(
    const float* __restrict__ x, const float* __restrict__ att,
    const float* __restrict__ w0, const float* __restrict__ b0,
    const float* __restrict__ w1, const float* __restrict__ b1,
    const float* __restrict__ w2, const float* __restrict__ b2,
    unsigned short* __restrict__ Qb, unsigned short* __restrict__ Kb,
    unsigned short* __restrict__ Vb)
{
  __shared__ char Xs[16384];           // 128 p-rows x 128 B; bounce: 64 x 256 B

  const int tid = threadIdx.x;
  const int m  = blockIdx.z;
  const int b  = blockIdx.y;
  const int pblock = blockIdx.x * 128;
  const float* src = m ? att : x;
  const int w = tid>>6, l = tid&63, lq = l>>4, lm = l&15;
  const int orow = 16*w + lm;

  const float* wAp = (m ? w1 : w0) + orow*64;
  bf16x8 aQ[2], aV[2] = {};
  {
    float4 a0 = *(const float4*)(wAp + lq*8);
    float4 a1 = *(const float4*)(wAp + lq*8 + 4);
    float4 a2 = *(const float4*)(wAp + 32 + lq*8);
    float4 a3 = *(const float4*)(wAp + 32 + lq*8 + 4);
    aQ[0] = pk8(a0, a1); aQ[1] = pk8(a2, a3);
    if (m == 0){
      const float* wBp = w2 + orow*64;
      float4 g0 = *(const float4*)(wBp + lq*8);
      float4 g1 = *(const float4*)(wBp + lq*8 + 4);
      float4 g2 = *(const float4*)(wBp + 32 + lq*8);
      float4 g3 = *(const float4*)(wBp + 32 + lq*8 + 4);
      aV[0] = pk8(g0, g1); aV[1] = pk8(g2, g3);
    }
  }
  float4 bQ4 = *(const float4*)((m ? b1 : b0) + 16*w + 4*lq);
  float4 bV4 = (m==0) ? *(const float4*)(b2 + 16*w + 4*lq) : (float4){0,0,0,0};

  const float* S = src + (size_t)b*NCH*NPOS + pblock;
  float4 xr[2][4];
  #pragma unroll
  for (int g=0; g<2; ++g){
    int unit = tid + 256*g;
    int q  = unit >> 5;
    int p4 = (unit & 31) << 2;
    #pragma unroll
    for (int j=0;j<4;j++)
      xr[g][j] = *(const float4*)(S + (size_t)(4*q+j)*NPOS + p4);
  }
  #pragma unroll
  for (int g=0; g<2; ++g){
    int unit = tid + 256*g;
    int q  = unit >> 5;
    int p4 = (unit & 31) << 2;
    const float* c0 = (const float*)&xr[g][0];
    const float* c1 = (const float*)&xr[g][1];
    const float* c2 = (const float*)&xr[g][2];
    const float* c3 = (const float*)&xr[g][3];
    #pragma unroll
    for (int u=0; u<4; ++u){
      uint2 pk;
      pk.x = pk2(c0[u], c1[u]);
      pk.y = pk2(c2[u], c3[u]);
      *(uint2*)(Xs + (p4+u)*128 + swz(p4+u, q*8)) = pk;
    }
  }
  __syncthreads();

  f32x4 accQ[8], accV[8];
  #pragma unroll
  for (int pt=0;pt<8;pt++){ accQ[pt]=(f32x4){0,0,0,0}; accV[pt]=(f32x4){0,0,0,0}; }
  #pragma unroll
  for (int pt=0; pt<8; ++pt){
    int prow = pt*16 + lm;
    bf16x8 bx0 = *(const bf16x8*)(Xs + prow*128 + swz(prow,      lq*16));
    bf16x8 bx1 = *(const bf16x8*)(Xs + prow*128 + swz(prow, 64 + lq*16));
    accQ[pt] = __builtin_amdgcn_mfma_f32_16x16x32_bf16(aQ[0], bx0, accQ[pt], 0,0,0);
    accQ[pt] = __builtin_amdgcn_mfma_f32_16x16x32_bf16(aQ[1], bx1, accQ[pt], 0,0,0);
    if (m == 0){
      accV[pt] = __builtin_amdgcn_mfma_f32_16x16x32_bf16(aV[0], bx0, accV[pt], 0,0,0);
      accV[pt] = __builtin_amdgcn_mfma_f32_16x16x32_bf16(aV[1], bx1, accV[pt], 0,0,0);
    }
  }

  unsigned short* dA = (m ? Kb : Qb) + (size_t)b*NCH*NPOS;
  unsigned short* dB = Vb + (size_t)b*NCH*NPOS;
  const float* bQv = (const float*)&bQ4;
  const float* bVv = (const float*)&bV4;
  const int skw = 32*((4*w + lq) & 7);

  __syncthreads();
  #pragma unroll
  for (int pt=0; pt<8; ++pt){
    #pragma unroll
    for (int r4=0;r4<4;r4++){
      int o = 16*w + 4*lq + r4;
      int p = pt*16 + lm;
      *(unsigned short*)(Xs + o*256 + ((2*p + skw) & 255)) =
          f2bf(fmaxf(accQ[pt][r4] + bQv[r4], 0.f));
    }
  }
  __syncthreads();
  {
    int o = tid >> 2, jj = tid & 3;
    int sk2 = 32*((o>>2)&7);
    #pragma unroll
    for (int i=0;i<4;i++){
      int j = i*4 + jj;
      uint4 v = *(const uint4*)(Xs + o*256 + ((j*16 + sk2) & 255));
      *(uint4*)(dA + (size_t)o*NPOS + pblock + j*8) = v;
    }
  }
  if (m == 0){
    __syncthreads();
    #pragma unroll
    for (int pt=0; pt<8; ++pt){
      #pragma unroll
      for (int r4=0;r4<4;r4++){
        int o = 16*w + 4*lq + r4;
        int p = pt*16 + lm;
        *(unsigned short*)(Xs + o*256 + ((2*p + skw) & 255)) =
            f2bf(fmaxf(accV[pt][r4] + bVv[r4], 0.f));
      }
    }
    __syncthreads();
    int o = tid >> 2, jj = tid & 3;
    int sk2 = 32*((o>>2)&7);
    #pragma unroll
    for (int i=0;i<4;i++){
      int j = i*4 + jj;
      uint4 v = *(const uint4*)(Xs + o*256 + ((j*16 + sk2) & 255));
      *(uint4*)(dB + (size_t)o*NPOS + pblock + j*8) = v;
    }
  }
}

// ---------------- Kernel 2: fused per-(b,c) MFMA attention ----------------
// 1024 blocks x 512 threads (8 waves — r4's verified geometry).
// 2 x 32KB buffers (64KB) -> 2 blocks/CU: two 8-wave barrier domains
// interleave on each CU. In-place dataflow:
//   X: Q rm -> QT -> VT -> M ;  Y: K rm -> KT -> A1 -> A2T
// Transposed staging uses paired-lane u32 writes (shfl_xor16 + v_perm):
// half the writes, 4-way conflict -> ~2-way.
__global__ __launch_bounds__(512, 4) void rc_attention_mfma(
    const unsigned short* __restrict__ Qb, const unsigned short* __restrict__ Kb,
    const unsigned short* __restrict__ Vb, unsigned short* __restrict__ Pb)
{
  extern __shared__ char lds[];
  char* X = lds;
  char* Y = lds + 32768;
  const int tid = threadIdx.x;
  const int l  = tid & 63;
  const int w  = tid >> 6;          // wave 0..7
  const int lq = l >> 4;            // quarter 0..3
  const int lm = l & 15;
  const size_t gbase = (size_t)blockIdx.x * NPOS;

  // Paired transposed write of one held uint4 set r[4] into buffer B.
  // Geometry per i: quad rows r0..r0+3 (r0 = 4w+32i), cols 8lm..8lm+7.
  #define TSTAGE(B, R)                                                      \
  { _Pragma("unroll")                                                       \
    for (int i=0;i<4;i++){                                                  \
      unsigned int od[4] = {R[i].x, R[i].y, R[i].z, R[i].w};                \
      unsigned int pd[4];                                                   \
      _Pragma("unroll")                                                     \
      for (int d=0;d<4;d++) pd[d] = (unsigned int)__shfl_xor((int)od[d],16);\
      const int ubase = (lq & 1) * 4;                                       \
      const int boff  = 8*w + 64*i + 4*(lq>>1);                             \
      _Pragma("unroll")                                                     \
      for (int uu=0; uu<4; ++uu){                                           \
        int u = ubase + uu; int d = u>>1;                                   \
        unsigned int sel = (u&1) ? 0x07060302u : 0x05040100u;               \
        unsigned int val = ((lq&1)==0)                                      \
            ? __builtin_amdgcn_perm(pd[d], od[d], sel)                      \
            : __builtin_amdgcn_perm(od[d], pd[d], sel);                     \
        int tr = 8*lm + u;                                                  \
        *(unsigned int*)((B) + tr*256 + swz(tr, boff)) = val;               \
      }                                                                     \
    } }

  // ---- load Q,K; stage rm (X,Y); regs held for T-restage ----
  uint4 qr[4], kr[4];
  #pragma unroll
  for (int i=0;i<4;i++){
    size_t e = (size_t)(tid + 512*i)*8;
    qr[i] = *(const uint4*)(Qb + gbase + e);
    kr[i] = *(const uint4*)(Kb + gbase + e);
  }
  #pragma unroll
  for (int i=0;i<4;i++){
    int e = (tid + 512*i)*8;
    int row = e >> 7, col = e & 127;
    *(uint4*)(X + row*256 + swz(row, col*2)) = qr[i];
    *(uint4*)(Y + row*256 + swz(row, col*2)) = kr[i];
  }
  __syncthreads();

  // ---- P1: S1T = K·Q^T. A-frag: K rows (Y), B-frag: Q rows (X). ----
  f32x4 acc1[8];
  #pragma unroll
  for (int t=0;t<8;t++) acc1[t] = (f32x4){0.f,0.f,0.f,0.f};
  {
    bf16x8 bq[4];
    #pragma unroll
    for (int kk=0;kk<4;kk++){
      int r = 16*w + lm;
      bq[kk] = *(const bf16x8*)(X + r*256 + swz(r, kk*64 + lq*16));
    }
    #pragma unroll
    for (int kk=0;kk<4;kk++){
      #pragma unroll
      for (int jt=0;jt<8;jt++){
        int jr = jt*16 + lm;
        bf16x8 ak = *(const bf16x8*)(Y + jr*256 + swz(jr, kk*64 + lq*16));
        acc1[jt] = __builtin_amdgcn_mfma_f32_16x16x32_bf16(ak, bq[kk], acc1[jt], 0,0,0);
      }
    }
  }
  unsigned int a1p[8][2];
  {
    float mx = -1e30f;
    #pragma unroll
    for (int t=0;t<8;t++)
      mx = fmaxf(mx, fmaxf(fmaxf(acc1[t][0], acc1[t][1]), fmaxf(acc1[t][2], acc1[t][3])));
    mx = fmaxf(mx, __shfl_xor(mx, 16));
    mx = fmaxf(mx, __shfl_xor(mx, 32));
    float sum = 0.f;
    #pragma unroll
    for (int t=0;t<8;t++){
      #pragma unroll
      for (int r4=0;r4<4;r4++){ float e = __expf(acc1[t][r4] - mx); acc1[t][r4] = e; sum += e; }
    }
    sum += __shfl_xor(sum, 16);
    sum += __shfl_xor(sum, 32);
    float inv = 1.f/sum;
    #pragma unroll
    for (int t=0;t<8;t++){
      a1p[t][0] = pk2(acc1[t][0]*inv, acc1[t][1]*inv);
      a1p[t][1] = pk2(acc1[t][2]*inv, acc1[t][3]*inv);
    }
  }
  // V prefetch (consumed 2 phases later)
  uint4 vr[4];
  #pragma unroll
  for (int i=0;i<4;i++)
    vr[i] = *(const uint4*)(Vb + gbase + (size_t)(tid + 512*i)*8);

  __syncthreads();                   // P1 reads of X,Y complete

  // ---- restage transposed: QT->X, KT->Y (paired u32 writes) ----
  TSTAGE(X, qr);
  TSTAGE(Y, kr);
  __syncthreads();

  // ---- P2: S2 = K^T·Q. A-frag: KT rows (Y), B-frag: QT rows (X). ----
  f32x4 acc2[8];
  #pragma unroll
  for (int t=0;t<8;t++) acc2[t] = (f32x4){0.f,0.f,0.f,0.f};
  {
    bf16x8 akt[4];
    #pragma unroll
    for (int kk=0;kk<4;kk++){
      int ir = 16*w + lm;
      akt[kk] = *(const bf16x8*)(Y + ir*256 + swz(ir, kk*64 + lq*16));
    }
    #pragma unroll
    for (int kk=0;kk<4;kk++){
      #pragma unroll
      for (int ct=0;ct<8;ct++){
        int jr = ct*16 + lm;
        bf16x8 bqt = *(const bf16x8*)(X + jr*256 + swz(jr, kk*64 + lq*16));
        acc2[ct] = __builtin_amdgcn_mfma_f32_16x16x32_bf16(akt[kk], bqt, acc2[ct], 0,0,0);
      }
    }
  }
  unsigned int a2p[8][2];
  {
    float m0=-1e30f, m1=-1e30f, m2=-1e30f, m3=-1e30f;
    #pragma unroll
    for (int t=0;t<8;t++){
      m0 = fmaxf(m0, acc2[t][0]); m1 = fmaxf(m1, acc2[t][1]);
      m2 = fmaxf(m2, acc2[t][2]); m3 = fmaxf(m3, acc2[t][3]);
    }
    #pragma unroll
    for (int d=1; d<16; d<<=1){
      m0 = fmaxf(m0, __shfl_xor(m0,d)); m1 = fmaxf(m1, __shfl_xor(m1,d));
      m2 = fmaxf(m2, __shfl_xor(m2,d)); m3 = fmaxf(m3, __shfl_xor(m3,d));
    }
    float s0=0.f, s1=0.f, s2=0.f, s3=0.f;
    #pragma unroll
    for (int t=0;t<8;t++){
      float e0 = __expf(acc2[t][0]-m0); acc2[t][0]=e0; s0 += e0;
      float e1 = __expf(acc2[t][1]-m1); acc2[t][1]=e1; s1 += e1;
      float e2 = __expf(acc2[t][2]-m2); acc2[t][2]=e2; s2 += e2;
      float e3 = __expf(acc2[t][3]-m3); acc2[t][3]=e3; s3 += e3;
    }
    #pragma unroll
    for (int d=1; d<16; d<<=1){
      s0 += __shfl_xor(s0,d); s1 += __shfl_xor(s1,d);
      s2 += __shfl_xor(s2,d); s3 += __shfl_xor(s3,d);
    }
    float i0=1.f/s0, i1=1.f/s1, i2=1.f/s2, i3=1.f/s3;
    #pragma unroll
    for (int t=0;t<8;t++){
      a2p[t][0] = pk2(acc2[t][0]*i0, acc2[t][1]*i1);
      a2p[t][1] = pk2(acc2[t][2]*i2, acc2[t][3]*i3);
    }
  }
  __syncthreads();                   // P2 reads of X,Y complete

  // ---- stage VT->X (paired), A1 rm->Y ----
  TSTAGE(X, vr);
  {
    int r = 16*w + lm;
    #pragma unroll
    for (int t=0;t<8;t++)
      *(uint2*)(Y + r*256 + swz(r, t*32 + lq*8)) = make_uint2(a1p[t][0], a1p[t][1]);
  }
  __syncthreads();

  // ---- P3: MT = VT·A1^T. A-frag: VT rows (X), B-frag: A1 rows (Y). ----
  f32x4 acc3[8];
  #pragma unroll
  for (int t=0;t<8;t++) acc3[t] = (f32x4){0.f,0.f,0.f,0.f};
  {
    bf16x8 av[4];
    #pragma unroll
    for (int kk=0;kk<4;kk++){
      int jr = 16*w + lm;
      av[kk] = *(const bf16x8*)(X + jr*256 + swz(jr, kk*64 + lq*16));
    }
    #pragma unroll
    for (int kk=0;kk<4;kk++){
      #pragma unroll
      for (int rt=0;rt<8;rt++){
        int rr = rt*16 + lm;
        bf16x8 ba = *(const bf16x8*)(Y + rr*256 + swz(rr, kk*64 + lq*16));
        acc3[rt] = __builtin_amdgcn_mfma_f32_16x16x32_bf16(av[kk], ba, acc3[rt], 0,0,0);
      }
    }
  }
  __syncthreads();                   // P3 reads of X,Y complete

  // ---- store M rm -> X (transposed frag store), A2T rm -> Y ----
  #pragma unroll
  for (int rt=0;rt<8;rt++){
    int rr = rt*16 + lm;
    *(uint2*)(X + rr*256 + swz(rr, 32*w + lq*8)) =
        make_uint2(pk2(acc3[rt][0], acc3[rt][1]),
                   pk2(acc3[rt][2], acc3[rt][3]));
  }
  #pragma unroll
  for (int t=0;t<8;t++){
    int jr = t*16 + lm;
    *(uint2*)(Y + jr*256 + swz(jr, 32*w + lq*8)) = make_uint2(a2p[t][0], a2p[t][1]);
  }
  __syncthreads();

  // ---- P4: P = M·A2. A-frag: M rows (X), B-frag: A2T rows (Y). ----
  f32x4 acc4[8];
  #pragma unroll
  for (int t=0;t<8;t++) acc4[t] = (f32x4){0.f,0.f,0.f,0.f};
  {
    bf16x8 am[4];
    #pragma unroll
    for (int kk=0;kk<4;kk++){
      int rr = 16*w + lm;
      am[kk] = *(const bf16x8*)(X + rr*256 + swz(rr, kk*64 + lq*16));
    }
    #pragma unroll
    for (int kk=0;kk<4;kk++){
      #pragma unroll
      for (int ct=0;ct<8;ct++){
        int jr = ct*16 + lm;
        bf16x8 ba2 = *(const bf16x8*)(Y + jr*256 + swz(jr, kk*64 + lq*16));
        acc4[ct] = __builtin_amdgcn_mfma_f32_16x16x32_bf16(am[kk], ba2, acc4[ct], 0,0,0);
      }
    }
  }
  unsigned short* pout = Pb + gbase;
  #pragma unroll
  for (int ct=0;ct<8;ct++){
    #pragma unroll
    for (int r4=0;r4<4;r4++){
      int rr = 16*w + lq*4 + r4;
      pout[rr*HH + ct*16 + lm] = f2bf(acc4[ct][r4]);
    }
  }
  #undef TSTAGE
}

// ---------------- Kernel 3: out = relu(conv1x1(P, w3, b3)) fp32, MFMA -----
// (unchanged from round 5/6 — verified fast)
__global__ __launch_bounds__(256, 6) void rc_conv_out(
    const unsigned short* __restrict__ Pb, const float* __restrict__ w3,
    const float* __restrict__ b3, float* __restrict__ out)
{
  __shared__ char Xs[16384];

  const int tid = threadIdx.x;
  const int b  = blockIdx.y;
  const int pblock = blockIdx.x * 128;
  const int w = tid>>6, l = tid&63, lq = l>>4, lm = l&15;
  const int orow = 16*w + lm;

  bf16x8 aW[2];
  {
    const float* wp = w3 + orow*64;
    float4 a0 = *(const float4*)(wp + lq*8);
    float4 a1 = *(const float4*)(wp + lq*8 + 4);
    float4 a2 = *(const float4*)(wp + 32 + lq*8);
    float4 a3 = *(const float4*)(wp + 32 + lq*8 + 4);
    aW[0] = pk8(a0, a1); aW[1] = pk8(a2, a3);
  }
  float4 bv4 = *(const float4*)(b3 + 16*w + 4*lq);
  const float* bv = (const float*)&bv4;

  const unsigned short* S = Pb + (size_t)b*NCH*NPOS + pblock;
  uint2 pr[2][4];
  #pragma unroll
  for (int g=0; g<2; ++g){
    int unit = tid + 256*g;
    int q  = unit >> 5;
    int p4 = (unit & 31) << 2;
    #pragma unroll
    for (int j=0;j<4;j++)
      pr[g][j] = *(const uint2*)(S + (size_t)(4*q+j)*NPOS + p4);
  }
  #pragma unroll
  for (int g=0; g<2; ++g){
    int unit = tid + 256*g;
    int q  = unit >> 5;
    int p4 = (unit & 31) << 2;
    const unsigned short* e0 = (const unsigned short*)&pr[g][0];
    const unsigned short* e1 = (const unsigned short*)&pr[g][1];
    const unsigned short* e2 = (const unsigned short*)&pr[g][2];
    const unsigned short* e3 = (const unsigned short*)&pr[g][3];
    #pragma unroll
    for (int u=0; u<4; ++u){
      uint2 pk;
      pk.x = (unsigned int)e0[u] | ((unsigned int)e1[u]<<16);
      pk.y = (unsigned int)e2[u] | ((unsigned int)e3[u]<<16);
      *(uint2*)(Xs + (p4+u)*128 + swz(p4+u, q*8)) = pk;
    }
  }
  __syncthreads();

  float* dst = out + (size_t)b*NCH*NPOS;
  #pragma unroll
  for (int pt=0; pt<8; ++pt){
    int prow = pt*16 + lm;
    bf16x8 bx0 = *(const bf16x8*)(Xs + prow*128 + swz(prow,      lq*16));
    bf16x8 bx1 = *(const bf16x8*)(Xs + prow*128 + swz(prow, 64 + lq*16));
    f32x4 acc = (f32x4){0.f,0.f,0.f,0.f};
    acc = __builtin_amdgcn_mfma_f32_16x16x32_bf16(aW[0], bx0, acc, 0,0,0);
    acc = __builtin_amdgcn_mfma_f32_16x16x32_bf16(aW[1], bx1, acc, 0,0,0);
    int p = pblock + pt*16 + lm;
    #pragma unroll
    for (int r4=0;r4<4;r4++){
      int o = 16*w + 4*lq + r4;
      dst[(size_t)o*NPOS + p] = fmaxf(acc[r4] + bv[r4], 0.f);
    }
  }
}

extern "C" void kernel_launch(void* const* d_in, const int* in_sizes, int n_in,
                              void* d_out, int out_size, void* d_ws, size_t ws_size,
                              hipStream_t stream)
{
  const float* x   = (const float*)d_in[0];
  const float* att = (const float*)d_in[1];
  const float* w0  = (const float*)d_in[2]; const float* b0 = (const float*)d_in[3];
  const float* w1  = (const float*)d_in[4]; const float* b1 = (const float*)d_in[5];
  const float* w2  = (const float*)d_in[6]; const float* b2 = (const float*)d_in[7];
  const float* w3  = (const float*)d_in[8]; const float* b3 = (const float*)d_in[9];

  const size_t NM = (size_t)NB*NCH*NPOS;          // 16,777,216 elems per matrix
  unsigned short* Qb = (unsigned short*)d_ws;     // bf16, 33.55 MB each
  unsigned short* Kb = Qb + NM;
  unsigned short* Vb = Kb + NM;
  unsigned short* Pb = Vb + NM;
  float* out = (float*)d_out;

  (void)hipFuncSetAttribute((const void*)rc_attention_mfma,
                            hipFuncAttributeMaxDynamicSharedMemorySize, 65536);

  rc_conv_in<<<dim3(128, NB, 2), 256, 0, stream>>>(x, att, w0,b0, w1,b1, w2,b2,
                                                   Qb, Kb, Vb);

  rc_attention_mfma<<<dim3(NB*NCH), 512, 65536, stream>>>(Qb, Kb, Vb, Pb);

  rc_conv_out<<<dim3(128, NB), 256, 0, stream>>>(Pb, w3, b3, out);
}

// Round 9
// 167.654 us; speedup vs baseline: 1.1679x; 1.1679x over previous
//
#include <hip/hip_runtime.h>
#include <stdint.h>

// Problem: B=16, C=64, H=W=128. fp32 in/out.
#define NB   16
#define NCH  64
#define HH   128
#define NPOS (HH*HH)        // 16384 spatial positions

typedef short bf16x8 __attribute__((ext_vector_type(8)));   // 8 bf16 = 4 VGPRs
typedef float f32x4  __attribute__((ext_vector_type(4)));

__device__ __forceinline__ unsigned short f2bf(float f){
  unsigned int u = __float_as_uint(f);
  u += 0x7FFFu + ((u>>16)&1u);          // RNE; inputs finite
  return (unsigned short)(u>>16);
}
__device__ __forceinline__ unsigned int pk2(float a, float b){
  return (unsigned int)f2bf(a) | ((unsigned int)f2bf(b)<<16);
}
__device__ __forceinline__ bf16x8 pk8(float4 a, float4 b){
  union { bf16x8 v; unsigned int u[4]; } r;
  r.u[0] = pk2(a.x, a.y); r.u[1] = pk2(a.z, a.w);
  r.u[2] = pk2(b.x, b.y); r.u[3] = pk2(b.z, b.w);
  return r.v;
}

// XOR swizzle on byte bits 4-6: spreads 16 consecutive rows over 8 16B slots.
__device__ __forceinline__ int swz(int row, int cb){
  return cb ^ (((row & 7) ^ ((row >> 3) & 7)) << 4);
}

// ---------------- Kernel 1: Q/V (m=0, from x) and K (m=1, from att) -------
// (unchanged — verified fast)
__global__ __launch_bounds__(256, 6) void rc_conv_in(
    const float* __restrict__ x, const float* __restrict__ att,
    const float* __restrict__ w0, const float* __restrict__ b0,
    const float* __restrict__ w1, const float* __restrict__ b1,
    const float* __restrict__ w2, const float* __restrict__ b2,
    unsigned short* __restrict__ Qb, unsigned short* __restrict__ Kb,
    unsigned short* __restrict__ Vb)
{
  __shared__ char Xs[16384];           // 128 p-rows x 128 B; bounce: 64 x 256 B

  const int tid = threadIdx.x;
  const int m  = blockIdx.z;
  const int b  = blockIdx.y;
  const int pblock = blockIdx.x * 128;
  const float* src = m ? att : x;
  const int w = tid>>6, l = tid&63, lq = l>>4, lm = l&15;
  const int orow = 16*w + lm;

  const float* wAp = (m ? w1 : w0) + orow*64;
  bf16x8 aQ[2], aV[2] = {};
  {
    float4 a0 = *(const float4*)(wAp + lq*8);
    float4 a1 = *(const float4*)(wAp + lq*8 + 4);
    float4 a2 = *(const float4*)(wAp + 32 + lq*8);
    float4 a3 = *(const float4*)(wAp + 32 + lq*8 + 4);
    aQ[0] = pk8(a0, a1); aQ[1] = pk8(a2, a3);
    if (m == 0){
      const float* wBp = w2 + orow*64;
      float4 g0 = *(const float4*)(wBp + lq*8);
      float4 g1 = *(const float4*)(wBp + lq*8 + 4);
      float4 g2 = *(const float4*)(wBp + 32 + lq*8);
      float4 g3 = *(const float4*)(wBp + 32 + lq*8 + 4);
      aV[0] = pk8(g0, g1); aV[1] = pk8(g2, g3);
    }
  }
  float4 bQ4 = *(const float4*)((m ? b1 : b0) + 16*w + 4*lq);
  float4 bV4 = (m==0) ? *(const float4*)(b2 + 16*w + 4*lq) : (float4){0,0,0,0};

  const float* S = src + (size_t)b*NCH*NPOS + pblock;
  float4 xr[2][4];
  #pragma unroll
  for (int g=0; g<2; ++g){
    int unit = tid + 256*g;
    int q  = unit >> 5;
    int p4 = (unit & 31) << 2;
    #pragma unroll
    for (int j=0;j<4;j++)
      xr[g][j] = *(const float4*)(S + (size_t)(4*q+j)*NPOS + p4);
  }
  #pragma unroll
  for (int g=0; g<2; ++g){
    int unit = tid + 256*g;
    int q  = unit >> 5;
    int p4 = (unit & 31) << 2;
    const float* c0 = (const float*)&xr[g][0];
    const float* c1 = (const float*)&xr[g][1];
    const float* c2 = (const float*)&xr[g][2];
    const float* c3 = (const float*)&xr[g][3];
    #pragma unroll
    for (int u=0; u<4; ++u){
      uint2 pk;
      pk.x = pk2(c0[u], c1[u]);
      pk.y = pk2(c2[u], c3[u]);
      *(uint2*)(Xs + (p4+u)*128 + swz(p4+u, q*8)) = pk;
    }
  }
  __syncthreads();

  f32x4 accQ[8], accV[8];
  #pragma unroll
  for (int pt=0;pt<8;pt++){ accQ[pt]=(f32x4){0,0,0,0}; accV[pt]=(f32x4){0,0,0,0}; }
  #pragma unroll
  for (int pt=0; pt<8; ++pt){
    int prow = pt*16 + lm;
    bf16x8 bx0 = *(const bf16x8*)(Xs + prow*128 + swz(prow,      lq*16));
    bf16x8 bx1 = *(const bf16x8*)(Xs + prow*128 + swz(prow, 64 + lq*16));
    accQ[pt] = __builtin_amdgcn_mfma_f32_16x16x32_bf16(aQ[0], bx0, accQ[pt], 0,0,0);
    accQ[pt] = __builtin_amdgcn_mfma_f32_16x16x32_bf16(aQ[1], bx1, accQ[pt], 0,0,0);
    if (m == 0){
      accV[pt] = __builtin_amdgcn_mfma_f32_16x16x32_bf16(aV[0], bx0, accV[pt], 0,0,0);
      accV[pt] = __builtin_amdgcn_mfma_f32_16x16x32_bf16(aV[1], bx1, accV[pt], 0,0,0);
    }
  }

  unsigned short* dA = (m ? Kb : Qb) + (size_t)b*NCH*NPOS;
  unsigned short* dB = Vb + (size_t)b*NCH*NPOS;
  const float* bQv = (const float*)&bQ4;
  const float* bVv = (const float*)&bV4;
  const int skw = 32*((4*w + lq) & 7);

  __syncthreads();
  #pragma unroll
  for (int pt=0; pt<8; ++pt){
    #pragma unroll
    for (int r4=0;r4<4;r4++){
      int o = 16*w + 4*lq + r4;
      int p = pt*16 + lm;
      *(unsigned short*)(Xs + o*256 + ((2*p + skw) & 255)) =
          f2bf(fmaxf(accQ[pt][r4] + bQv[r4], 0.f));
    }
  }
  __syncthreads();
  {
    int o = tid >> 2, jj = tid & 3;
    int sk2 = 32*((o>>2)&7);
    #pragma unroll
    for (int i=0;i<4;i++){
      int j = i*4 + jj;
      uint4 v = *(const uint4*)(Xs + o*256 + ((j*16 + sk2) & 255));
      *(uint4*)(dA + (size_t)o*NPOS + pblock + j*8) = v;
    }
  }
  if (m == 0){
    __syncthreads();
    #pragma unroll
    for (int pt=0; pt<8; ++pt){
      #pragma unroll
      for (int r4=0;r4<4;r4++){
        int o = 16*w + 4*lq + r4;
        int p = pt*16 + lm;
        *(unsigned short*)(Xs + o*256 + ((2*p + skw) & 255)) =
            f2bf(fmaxf(accV[pt][r4] + bVv[r4], 0.f));
      }
    }
    __syncthreads();
    int o = tid >> 2, jj = tid & 3;
    int sk2 = 32*((o>>2)&7);
    #pragma unroll
    for (int i=0;i<4;i++){
      int j = i*4 + jj;
      uint4 v = *(const uint4*)(Xs + o*256 + ((j*16 + sk2) & 255));
      *(uint4*)(dB + (size_t)o*NPOS + pblock + j*8) = v;
    }
  }
}

// ---------------- Kernel 2: fused per-(b,c) MFMA attention ----------------
// 1024 blocks x 512 threads (8 waves). 2 x 32KB buffers (64KB) -> target
// 2 blocks/CU (needs VGPR<=128 — NO min-waves launch_bounds arg: r7 showed
// forcing it causes a 64-VGPR spill catastrophe; let the allocator breathe).
// In-place dataflow: X: Q rm -> QT -> VT -> M ; Y: K rm -> KT -> A1 -> A2T.
__global__ __launch_bounds__(512) void rc_attention_mfma(
    const unsigned short* __restrict__ Qb, const unsigned short* __restrict__ Kb,
    const unsigned short* __restrict__ Vb, unsigned short* __restrict__ Pb)
{
  extern __shared__ char lds[];
  char* X = lds;
  char* Y = lds + 32768;
  const int tid = threadIdx.x;
  const int l  = tid & 63;
  const int w  = tid >> 6;          // wave 0..7
  const int lq = l >> 4;            // quarter 0..3
  const int lm = l & 15;
  const size_t gbase = (size_t)blockIdx.x * NPOS;

  // Paired transposed write of one held uint4 set R[4] into buffer B.
  // Thread rows: 4w+lq+32i, cols 8lm..8lm+7. Lane pairs (lq^1) split the
  // 8 T-rows: even-lq writes u=0..3, odd-lq u=4..7, packing both rows of
  // the pair into one u32 via v_perm. Half the writes of scalar staging.
  #define TSTAGE(B, R)                                                      \
  { _Pragma("unroll")                                                       \
    for (int i=0;i<4;i++){                                                  \
      unsigned int od[4] = {R[i].x, R[i].y, R[i].z, R[i].w};                \
      unsigned int pd[4];                                                   \
      _Pragma("unroll")                                                     \
      for (int d=0;d<4;d++) pd[d] = (unsigned int)__shfl_xor((int)od[d],16);\
      const int ubase = (lq & 1) * 4;                                       \
      const int boff  = 8*w + 64*i + 4*(lq>>1);                             \
      _Pragma("unroll")                                                     \
      for (int uu=0; uu<4; ++uu){                                           \
        int u = ubase + uu; int d = u>>1;                                   \
        unsigned int sel = (u&1) ? 0x07060302u : 0x05040100u;               \
        unsigned int val = ((lq&1)==0)                                      \
            ? __builtin_amdgcn_perm(pd[d], od[d], sel)                      \
            : __builtin_amdgcn_perm(od[d], pd[d], sel);                     \
        int tr = 8*lm + u;                                                  \
        *(unsigned int*)((B) + tr*256 + swz(tr, boff)) = val;               \
      }                                                                     \
    } }

  // ---- load Q,K; stage rm (X,Y); regs held for T-restage ----
  uint4 qr[4], kr[4];
  #pragma unroll
  for (int i=0;i<4;i++){
    size_t e = (size_t)(tid + 512*i)*8;
    qr[i] = *(const uint4*)(Qb + gbase + e);
    kr[i] = *(const uint4*)(Kb + gbase + e);
  }
  #pragma unroll
  for (int i=0;i<4;i++){
    int e = (tid + 512*i)*8;
    int row = e >> 7, col = e & 127;
    *(uint4*)(X + row*256 + swz(row, col*2)) = qr[i];
    *(uint4*)(Y + row*256 + swz(row, col*2)) = kr[i];
  }
  __syncthreads();

  // ---- P1: S1T = K·Q^T. A-frag: K rows (Y), B-frag: Q rows (X). ----
  f32x4 acc1[8];
  #pragma unroll
  for (int t=0;t<8;t++) acc1[t] = (f32x4){0.f,0.f,0.f,0.f};
  {
    bf16x8 bq[4];
    #pragma unroll
    for (int kk=0;kk<4;kk++){
      int r = 16*w + lm;
      bq[kk] = *(const bf16x8*)(X + r*256 + swz(r, kk*64 + lq*16));
    }
    #pragma unroll
    for (int kk=0;kk<4;kk++){
      #pragma unroll
      for (int jt=0;jt<8;jt++){
        int jr = jt*16 + lm;
        bf16x8 ak = *(const bf16x8*)(Y + jr*256 + swz(jr, kk*64 + lq*16));
        acc1[jt] = __builtin_amdgcn_mfma_f32_16x16x32_bf16(ak, bq[kk], acc1[jt], 0,0,0);
      }
    }
  }
  unsigned int a1p[8][2];
  {
    float mx = -1e30f;
    #pragma unroll
    for (int t=0;t<8;t++)
      mx = fmaxf(mx, fmaxf(fmaxf(acc1[t][0], acc1[t][1]), fmaxf(acc1[t][2], acc1[t][3])));
    mx = fmaxf(mx, __shfl_xor(mx, 16));
    mx = fmaxf(mx, __shfl_xor(mx, 32));
    float sum = 0.f;
    #pragma unroll
    for (int t=0;t<8;t++){
      #pragma unroll
      for (int r4=0;r4<4;r4++){ float e = __expf(acc1[t][r4] - mx); acc1[t][r4] = e; sum += e; }
    }
    sum += __shfl_xor(sum, 16);
    sum += __shfl_xor(sum, 32);
    float inv = 1.f/sum;
    #pragma unroll
    for (int t=0;t<8;t++){
      a1p[t][0] = pk2(acc1[t][0]*inv, acc1[t][1]*inv);
      a1p[t][1] = pk2(acc1[t][2]*inv, acc1[t][3]*inv);
    }
  }
  __syncthreads();                   // P1 reads of X,Y complete

  // ---- restage transposed: QT->X, KT->Y; qr/kr die here ----
  TSTAGE(X, qr);
  TSTAGE(Y, kr);
  // V prefetch issued as qr/kr retire (latency hides under barrier+P2)
  uint4 vr[4];
  #pragma unroll
  for (int i=0;i<4;i++)
    vr[i] = *(const uint4*)(Vb + gbase + (size_t)(tid + 512*i)*8);
  __syncthreads();

  // ---- P2: S2 = K^T·Q. A-frag: KT rows (Y), B-frag: QT rows (X). ----
  f32x4 acc2[8];
  #pragma unroll
  for (int t=0;t<8;t++) acc2[t] = (f32x4){0.f,0.f,0.f,0.f};
  {
    bf16x8 akt[4];
    #pragma unroll
    for (int kk=0;kk<4;kk++){
      int ir = 16*w + lm;
      akt[kk] = *(const bf16x8*)(Y + ir*256 + swz(ir, kk*64 + lq*16));
    }
    #pragma unroll
    for (int kk=0;kk<4;kk++){
      #pragma unroll
      for (int ct=0;ct<8;ct++){
        int jr = ct*16 + lm;
        bf16x8 bqt = *(const bf16x8*)(X + jr*256 + swz(jr, kk*64 + lq*16));
        acc2[ct] = __builtin_amdgcn_mfma_f32_16x16x32_bf16(akt[kk], bqt, acc2[ct], 0,0,0);
      }
    }
  }
  unsigned int a2p[8][2];
  {
    float m0=-1e30f, m1=-1e30f, m2=-1e30f, m3=-1e30f;
    #pragma unroll
    for (int t=0;t<8;t++){
      m0 = fmaxf(m0, acc2[t][0]); m1 = fmaxf(m1, acc2[t][1]);
      m2 = fmaxf(m2, acc2[t][2]); m3 = fmaxf(m3, acc2[t][3]);
    }
    #pragma unroll
    for (int d=1; d<16; d<<=1){
      m0 = fmaxf(m0, __shfl_xor(m0,d)); m1 = fmaxf(m1, __shfl_xor(m1,d));
      m2 = fmaxf(m2, __shfl_xor(m2,d)); m3 = fmaxf(m3, __shfl_xor(m3,d));
    }
    float s0=0.f, s1=0.f, s2=0.f, s3=0.f;
    #pragma unroll
    for (int t=0;t<8;t++){
      float e0 = __expf(acc2[t][0]-m0); acc2[t][0]=e0; s0 += e0;
      float e1 = __expf(acc2[t][1]-m1); acc2[t][1]=e1; s1 += e1;
      float e2 = __expf(acc2[t][2]-m2); acc2[t][2]=e2; s2 += e2;
      float e3 = __expf(acc2[t][3]-m3); acc2[t][3]=e3; s3 += e3;
    }
    #pragma unroll
    for (int d=1; d<16; d<<=1){
      s0 += __shfl_xor(s0,d); s1 += __shfl_xor(s1,d);
      s2 += __shfl_xor(s2,d); s3 += __shfl_xor(s3,d);
    }
    float i0=1.f/s0, i1=1.f/s1, i2=1.f/s2, i3=1.f/s3;
    #pragma unroll
    for (int t=0;t<8;t++){
      a2p[t][0] = pk2(acc2[t][0]*i0, acc2[t][1]*i1);
      a2p[t][1] = pk2(acc2[t][2]*i2, acc2[t][3]*i3);
    }
  }
  __syncthreads();                   // P2 reads of X,Y complete

  // ---- stage VT->X (paired), A1 rm->Y ----
  TSTAGE(X, vr);
  {
    int r = 16*w + lm;
    #pragma unroll
    for (int t=0;t<8;t++)
      *(uint2*)(Y + r*256 + swz(r, t*32 + lq*8)) = make_uint2(a1p[t][0], a1p[t][1]);
  }
  __syncthreads();

  // ---- P3: MT = VT·A1^T. A-frag: VT rows (X), B-frag: A1 rows (Y). ----
  f32x4 acc3[8];
  #pragma unroll
  for (int t=0;t<8;t++) acc3[t] = (f32x4){0.f,0.f,0.f,0.f};
  {
    bf16x8 av[4];
    #pragma unroll
    for (int kk=0;kk<4;kk++){
      int jr = 16*w + lm;
      av[kk] = *(const bf16x8*)(X + jr*256 + swz(jr, kk*64 + lq*16));
    }
    #pragma unroll
    for (int kk=0;kk<4;kk++){
      #pragma unroll
      for (int rt=0;rt<8;rt++){
        int rr = rt*16 + lm;
        bf16x8 ba = *(const bf16x8*)(Y + rr*256 + swz(rr, kk*64 + lq*16));
        acc3[rt] = __builtin_amdgcn_mfma_f32_16x16x32_bf16(av[kk], ba, acc3[rt], 0,0,0);
      }
    }
  }
  __syncthreads();                   // P3 reads of X,Y complete

  // ---- store M rm -> X (transposed frag store), A2T rm -> Y ----
  #pragma unroll
  for (int rt=0;rt<8;rt++){
    int rr = rt*16 + lm;
    *(uint2*)(X + rr*256 + swz(rr, 32*w + lq*8)) =
        make_uint2(pk2(acc3[rt][0], acc3[rt][1]),
                   pk2(acc3[rt][2], acc3[rt][3]));
  }
  #pragma unroll
  for (int t=0;t<8;t++){
    int jr = t*16 + lm;
    *(uint2*)(Y + jr*256 + swz(jr, 32*w + lq*8)) = make_uint2(a2p[t][0], a2p[t][1]);
  }
  __syncthreads();

  // ---- P4: P = M·A2. A-frag: M rows (X), B-frag: A2T rows (Y). ----
  f32x4 acc4[8];
  #pragma unroll
  for (int t=0;t<8;t++) acc4[t] = (f32x4){0.f,0.f,0.f,0.f};
  {
    bf16x8 am[4];
    #pragma unroll
    for (int kk=0;kk<4;kk++){
      int rr = 16*w + lm;
      am[kk] = *(const bf16x8*)(X + rr*256 + swz(rr, kk*64 + lq*16));
    }
    #pragma unroll
    for (int kk=0;kk<4;kk++){
      #pragma unroll
      for (int ct=0;ct<8;ct++){
        int jr = ct*16 + lm;
        bf16x8 ba2 = *(const bf16x8*)(Y + jr*256 + swz(jr, kk*64 + lq*16));
        acc4[ct] = __builtin_amdgcn_mfma_f32_16x16x32_bf16(am[kk], ba2, acc4[ct], 0,0,0);
      }
    }
  }
  unsigned short* pout = Pb + gbase;
  #pragma unroll
  for (int ct=0;ct<8;ct++){
    #pragma unroll
    for (int r4=0;r4<4;r4++){
      int rr = 16*w + lq*4 + r4;
      pout[rr*HH + ct*16 + lm] = f2bf(acc4[ct][r4]);
    }
  }
  #undef TSTAGE
}

// ---------------- Kernel 3: out = relu(conv1x1(P, w3, b3)) fp32, MFMA -----
// (unchanged — verified fast)
__global__ __launch_bounds__(256, 6) void rc_conv_out(
    const unsigned short* __restrict__ Pb, const float* __restrict__ w3,
    const float* __restrict__ b3, float* __restrict__ out)
{
  __shared__ char Xs[16384];

  const int tid = threadIdx.x;
  const int b  = blockIdx.y;
  const int pblock = blockIdx.x * 128;
  const int w = tid>>6, l = tid&63, lq = l>>4, lm = l&15;
  const int orow = 16*w + lm;

  bf16x8 aW[2];
  {
    const float* wp = w3 + orow*64;
    float4 a0 = *(const float4*)(wp + lq*8);
    float4 a1 = *(const float4*)(wp + lq*8 + 4);
    float4 a2 = *(const float4*)(wp + 32 + lq*8);
    float4 a3 = *(const float4*)(wp + 32 + lq*8 + 4);
    aW[0] = pk8(a0, a1); aW[1] = pk8(a2, a3);
  }
  float4 bv4 = *(const float4*)(b3 + 16*w + 4*lq);
  const float* bv = (const float*)&bv4;

  const unsigned short* S = Pb + (size_t)b*NCH*NPOS + pblock;
  uint2 pr[2][4];
  #pragma unroll
  for (int g=0; g<2; ++g){
    int unit = tid + 256*g;
    int q  = unit >> 5;
    int p4 = (unit & 31) << 2;
    #pragma unroll
    for (int j=0;j<4;j++)
      pr[g][j] = *(const uint2*)(S + (size_t)(4*q+j)*NPOS + p4);
  }
  #pragma unroll
  for (int g=0; g<2; ++g){
    int unit = tid + 256*g;
    int q  = unit >> 5;
    int p4 = (unit & 31) << 2;
    const unsigned short* e0 = (const unsigned short*)&pr[g][0];
    const unsigned short* e1 = (const unsigned short*)&pr[g][1];
    const unsigned short* e2 = (const unsigned short*)&pr[g][2];
    const unsigned short* e3 = (const unsigned short*)&pr[g][3];
    #pragma unroll
    for (int u=0; u<4; ++u){
      uint2 pk;
      pk.x = (unsigned int)e0[u] | ((unsigned int)e1[u]<<16);
      pk.y = (unsigned int)e2[u] | ((unsigned int)e3[u]<<16);
      *(uint2*)(Xs + (p4+u)*128 + swz(p4+u, q*8)) = pk;
    }
  }
  __syncthreads();

  float* dst = out + (size_t)b*NCH*NPOS;
  #pragma unroll
  for (int pt=0; pt<8; ++pt){
    int prow = pt*16 + lm;
    bf16x8 bx0 = *(const bf16x8*)(Xs + prow*128 + swz(prow,      lq*16));
    bf16x8 bx1 = *(const bf16x8*)(Xs + prow*128 + swz(prow, 64 + lq*16));
    f32x4 acc = (f32x4){0.f,0.f,0.f,0.f};
    acc = __builtin_amdgcn_mfma_f32_16x16x32_bf16(aW[0], bx0, acc, 0,0,0);
    acc = __builtin_amdgcn_mfma_f32_16x16x32_bf16(aW[1], bx1, acc, 0,0,0);
    int p = pblock + pt*16 + lm;
    #pragma unroll
    for (int r4=0;r4<4;r4++){
      int o = 16*w + 4*lq + r4;
      dst[(size_t)o*NPOS + p] = fmaxf(acc[r4] + bv[r4], 0.f);
    }
  }
}

extern "C" void kernel_launch(void* const* d_in, const int* in_sizes, int n_in,
                              void* d_out, int out_size, void* d_ws, size_t ws_size,
                              hipStream_t stream)
{
  const float* x   = (const float*)d_in[0];
  const float* att = (const float*)d_in[1];
  const float* w0  = (const float*)d_in[2]; const float* b0 = (const float*)d_in[3];
  const float* w1  = (const float*)d_in[4]; const float* b1 = (const float*)d_in[5];
  const float* w2  = (const float*)d_in[6]; const float* b2 = (const float*)d_in[7];
  const float* w3  = (const float*)d_in[8]; const float* b3 = (const float*)d_in[9];

  const size_t NM = (size_t)NB*NCH*NPOS;          // 16,777,216 elems per matrix
  unsigned short* Qb = (unsigned short*)d_ws;     // bf16, 33.55 MB each
  unsigned short* Kb = Qb + NM;
  unsigned short* Vb = Kb + NM;
  unsigned short* Pb = Vb + NM;
  float* out = (float*)d_out;

  (void)hipFuncSetAttribute((const void*)rc_attention_mfma,
                            hipFuncAttributeMaxDynamicSharedMemorySize, 65536);

  rc_conv_in<<<dim3(128, NB, 2), 256, 0, stream>>>(x, att, w0,b0, w1,b1, w2,b2,
                                                   Qb, Kb, Vb);

  rc_attention_mfma<<<dim3(NB*NCH), 512, 65536, stream>>>(Qb, Kb, Vb, Pb);

  rc_conv_out<<<dim3(128, NB), 256, 0, stream>>>(Pb, w3, b3, out);
}

// Round 12
// 139.487 us; speedup vs baseline: 1.4037x; 1.2019x over previous
//
#include <hip/hip_runtime.h>
#include <stdint.h>

// Problem: B=16, C=64, H=W=128. fp32 in/out.
#define NB   16
#define NCH  64
#define HH   128
#define NPOS (HH*HH)        // 16384 spatial positions

typedef short bf16x8 __attribute__((ext_vector_type(8)));   // 8 bf16 = 4 VGPRs
typedef float f32x4  __attribute__((ext_vector_type(4)));

__device__ __forceinline__ unsigned short f2bf(float f){
  unsigned int u = __float_as_uint(f);
  u += 0x7FFFu + ((u>>16)&1u);          // RNE; inputs finite
  return (unsigned short)(u>>16);
}
__device__ __forceinline__ unsigned int pk2(float a, float b){
  return (unsigned int)f2bf(a) | ((unsigned int)f2bf(b)<<16);
}
__device__ __forceinline__ bf16x8 pk8(float4 a, float4 b){
  union { bf16x8 v; unsigned int u[4]; } r;
  r.u[0] = pk2(a.x, a.y); r.u[1] = pk2(a.z, a.w);
  r.u[2] = pk2(b.x, b.y); r.u[3] = pk2(b.z, b.w);
  return r.v;
}

// XOR swizzle on byte bits 4-6: spreads 16 consecutive rows over 8 16B slots.
__device__ __forceinline__ int swz(int row, int cb){
  return cb ^ (((row & 7) ^ ((row >> 3) & 7)) << 4);
}

// ---------------- Kernel 1: Q/V (m=0, from x) and K (m=1, from att) -------
// (r5-r9 version — verified fast: 16KB LDS, W frags direct from global)
__global__ __launch_bounds__(256, 6) void rc_conv_in(
    const float* __restrict__ x, const float* __restrict__ att,
    const float* __restrict__ w0, const float* __restrict__ b0,
    const float* __restrict__ w1, const float* __restrict__ b1,
    const float* __restrict__ w2, const float* __restrict__ b2,
    unsigned short* __restrict__ Qb, unsigned short* __restrict__ Kb,
    unsigned short* __restrict__ Vb)
{
  __shared__ char Xs[16384];           // 128 p-rows x 128 B; bounce: 64 x 256 B

  const int tid = threadIdx.x;
  const int m  = blockIdx.z;
  const int b  = blockIdx.y;
  const int pblock = blockIdx.x * 128;
  const float* src = m ? att : x;
  const int w = tid>>6, l = tid&63, lq = l>>4, lm = l&15;
  const int orow = 16*w + lm;

  const float* wAp = (m ? w1 : w0) + orow*64;
  bf16x8 aQ[2], aV[2] = {};
  {
    float4 a0 = *(const float4*)(wAp + lq*8);
    float4 a1 = *(const float4*)(wAp + lq*8 + 4);
    float4 a2 = *(const float4*)(wAp + 32 + lq*8);
    float4 a3 = *(const float4*)(wAp + 32 + lq*8 + 4);
    aQ[0] = pk8(a0, a1); aQ[1] = pk8(a2, a3);
    if (m == 0){
      const float* wBp = w2 + orow*64;
      float4 g0 = *(const float4*)(wBp + lq*8);
      float4 g1 = *(const float4*)(wBp + lq*8 + 4);
      float4 g2 = *(const float4*)(wBp + 32 + lq*8);
      float4 g3 = *(const float4*)(wBp + 32 + lq*8 + 4);
      aV[0] = pk8(g0, g1); aV[1] = pk8(g2, g3);
    }
  }
  float4 bQ4 = *(const float4*)((m ? b1 : b0) + 16*w + 4*lq);
  float4 bV4 = (m==0) ? *(const float4*)(b2 + 16*w + 4*lq) : (float4){0,0,0,0};

  const float* S = src + (size_t)b*NCH*NPOS + pblock;
  float4 xr[2][4];
  #pragma unroll
  for (int g=0; g<2; ++g){
    int unit = tid + 256*g;
    int q  = unit >> 5;
    int p4 = (unit & 31) << 2;
    #pragma unroll
    for (int j=0;j<4;j++)
      xr[g][j] = *(const float4*)(S + (size_t)(4*q+j)*NPOS + p4);
  }
  #pragma unroll
  for (int g=0; g<2; ++g){
    int unit = tid + 256*g;
    int q  = unit >> 5;
    int p4 = (unit & 31) << 2;
    const float* c0 = (const float*)&xr[g][0];
    const float* c1 = (const float*)&xr[g][1];
    const float* c2 = (const float*)&xr[g][2];
    const float* c3 = (const float*)&xr[g][3];
    #pragma unroll
    for (int u=0; u<4; ++u){
      uint2 pk;
      pk.x = pk2(c0[u], c1[u]);
      pk.y = pk2(c2[u], c3[u]);
      *(uint2*)(Xs + (p4+u)*128 + swz(p4+u, q*8)) = pk;
    }
  }
  __syncthreads();

  f32x4 accQ[8], accV[8];
  #pragma unroll
  for (int pt=0;pt<8;pt++){ accQ[pt]=(f32x4){0,0,0,0}; accV[pt]=(f32x4){0,0,0,0}; }
  #pragma unroll
  for (int pt=0; pt<8; ++pt){
    int prow = pt*16 + lm;
    bf16x8 bx0 = *(const bf16x8*)(Xs + prow*128 + swz(prow,      lq*16));
    bf16x8 bx1 = *(const bf16x8*)(Xs + prow*128 + swz(prow, 64 + lq*16));
    accQ[pt] = __builtin_amdgcn_mfma_f32_16x16x32_bf16(aQ[0], bx0, accQ[pt], 0,0,0);
    accQ[pt] = __builtin_amdgcn_mfma_f32_16x16x32_bf16(aQ[1], bx1, accQ[pt], 0,0,0);
    if (m == 0){
      accV[pt] = __builtin_amdgcn_mfma_f32_16x16x32_bf16(aV[0], bx0, accV[pt], 0,0,0);
      accV[pt] = __builtin_amdgcn_mfma_f32_16x16x32_bf16(aV[1], bx1, accV[pt], 0,0,0);
    }
  }

  unsigned short* dA = (m ? Kb : Qb) + (size_t)b*NCH*NPOS;
  unsigned short* dB = Vb + (size_t)b*NCH*NPOS;
  const float* bQv = (const float*)&bQ4;
  const float* bVv = (const float*)&bV4;
  const int skw = 32*((4*w + lq) & 7);

  __syncthreads();
  #pragma unroll
  for (int pt=0; pt<8; ++pt){
    #pragma unroll
    for (int r4=0;r4<4;r4++){
      int o = 16*w + 4*lq + r4;
      int p = pt*16 + lm;
      *(unsigned short*)(Xs + o*256 + ((2*p + skw) & 255)) =
          f2bf(fmaxf(accQ[pt][r4] + bQv[r4], 0.f));
    }
  }
  __syncthreads();
  {
    int o = tid >> 2, jj = tid & 3;
    int sk2 = 32*((o>>2)&7);
    #pragma unroll
    for (int i=0;i<4;i++){
      int j = i*4 + jj;
      uint4 v = *(const uint4*)(Xs + o*256 + ((j*16 + sk2) & 255));
      *(uint4*)(dA + (size_t)o*NPOS + pblock + j*8) = v;
    }
  }
  if (m == 0){
    __syncthreads();
    #pragma unroll
    for (int pt=0; pt<8; ++pt){
      #pragma unroll
      for (int r4=0;r4<4;r4++){
        int o = 16*w + 4*lq + r4;
        int p = pt*16 + lm;
        *(unsigned short*)(Xs + o*256 + ((2*p + skw) & 255)) =
            f2bf(fmaxf(accV[pt][r4] + bVv[r4], 0.f));
      }
    }
    __syncthreads();
    int o = tid >> 2, jj = tid & 3;
    int sk2 = 32*((o>>2)&7);
    #pragma unroll
    for (int i=0;i<4;i++){
      int j = i*4 + jj;
      uint4 v = *(const uint4*)(Xs + o*256 + ((j*16 + sk2) & 255));
      *(uint4*)(dB + (size_t)o*NPOS + pblock + j*8) = v;
    }
  }
}

// ---------------- Kernel 2: fused per-(b,c) MFMA attention ----------------
// ROUND-4 VERIFIED VERSION (78 µs profiled, VGPR 112): 1024 blocks x 512
// threads (8 waves), 4 x 32KB buffers (131KB LDS, 1 block/CU). Single
// staging phase (Q,K rm + transposed together) -> P1,P2 back-to-back;
// only 4 barriers + epilogue. Verified numerics since round 4.
__global__ __launch_bounds__(512) void rc_attention_mfma(
    const unsigned short* __restrict__ Qb, const unsigned short* __restrict__ Kb,
    const unsigned short* __restrict__ Vb, unsigned short* __restrict__ Pb)
{
  extern __shared__ char lds[];
  char* B0 = lds;
  char* B1 = lds + 32768;
  char* B2 = lds + 65536;
  char* B3 = lds + 98304;
  const int tid = threadIdx.x;
  const int l  = tid & 63;
  const int w  = tid >> 6;          // wave 0..7
  const int lq = l >> 4;            // quarter 0..3
  const int lm = l & 15;
  const size_t gbase = (size_t)blockIdx.x * NPOS;

  // ---- V global loads early (held in regs through P1/P2) ----
  uint4 vreg[4];
  #pragma unroll
  for (int i=0;i<4;i++)
    vreg[i] = *(const uint4*)(Vb + gbase + (size_t)(tid + 512*i)*8);

  // ---- stage Q,K row-major + transposed ----
  #pragma unroll
  for (int i=0;i<4;i++){
    int e = (tid + 512*i)*8;
    int row = e >> 7, col = e & 127;
    uint4 q = *(const uint4*)(Qb + gbase + e);
    uint4 k = *(const uint4*)(Kb + gbase + e);
    *(uint4*)(B0 + row*256 + swz(row, col*2)) = q;
    *(uint4*)(B1 + row*256 + swz(row, col*2)) = k;
    unsigned int qd[4] = {q.x,q.y,q.z,q.w};
    unsigned int kd[4] = {k.x,k.y,k.z,k.w};
    #pragma unroll
    for (int u=0;u<8;u++){
      unsigned short qe = (unsigned short)(qd[u>>1] >> (16*(u&1)));
      unsigned short ke = (unsigned short)(kd[u>>1] >> (16*(u&1)));
      int tr = col + u;             // T-row = original col
      *(unsigned short*)(B2 + tr*256 + swz(tr, row*2)) = qe;
      *(unsigned short*)(B3 + tr*256 + swz(tr, row*2)) = ke;
    }
  }
  __syncthreads();

  // ---- P1: S1T = K * Q^T ----
  f32x4 acc1[8];
  #pragma unroll
  for (int t=0;t<8;t++) acc1[t] = (f32x4){0.f,0.f,0.f,0.f};
  {
    bf16x8 bq[4];
    #pragma unroll
    for (int kk=0;kk<4;kk++){
      int r = 16*w + lm;
      bq[kk] = *(const bf16x8*)(B0 + r*256 + swz(r, kk*64 + lq*16));
    }
    #pragma unroll
    for (int kk=0;kk<4;kk++){
      #pragma unroll
      for (int jt=0;jt<8;jt++){
        int jr = jt*16 + lm;
        bf16x8 ak = *(const bf16x8*)(B1 + jr*256 + swz(jr, kk*64 + lq*16));
        acc1[jt] = __builtin_amdgcn_mfma_f32_16x16x32_bf16(ak, bq[kk], acc1[jt], 0,0,0);
      }
    }
  }
  unsigned int a1p[8][2];
  {
    float mx = -1e30f;
    #pragma unroll
    for (int t=0;t<8;t++)
      mx = fmaxf(mx, fmaxf(fmaxf(acc1[t][0], acc1[t][1]), fmaxf(acc1[t][2], acc1[t][3])));
    mx = fmaxf(mx, __shfl_xor(mx, 16));
    mx = fmaxf(mx, __shfl_xor(mx, 32));
    float sum = 0.f;
    #pragma unroll
    for (int t=0;t<8;t++){
      #pragma unroll
      for (int r4=0;r4<4;r4++){ float e = __expf(acc1[t][r4] - mx); acc1[t][r4] = e; sum += e; }
    }
    sum += __shfl_xor(sum, 16);
    sum += __shfl_xor(sum, 32);
    float inv = 1.f/sum;
    #pragma unroll
    for (int t=0;t<8;t++){
      a1p[t][0] = pk2(acc1[t][0]*inv, acc1[t][1]*inv);
      a1p[t][1] = pk2(acc1[t][2]*inv, acc1[t][3]*inv);
    }
  }

  // ---- P2: S2 = K^T * Q ----
  f32x4 acc2[8];
  #pragma unroll
  for (int t=0;t<8;t++) acc2[t] = (f32x4){0.f,0.f,0.f,0.f};
  {
    bf16x8 akt[4];
    #pragma unroll
    for (int kk=0;kk<4;kk++){
      int ir = 16*w + lm;
      akt[kk] = *(const bf16x8*)(B3 + ir*256 + swz(ir, kk*64 + lq*16));
    }
    #pragma unroll
    for (int kk=0;kk<4;kk++){
      #pragma unroll
      for (int ct=0;ct<8;ct++){
        int jr = ct*16 + lm;
        bf16x8 bqt = *(const bf16x8*)(B2 + jr*256 + swz(jr, kk*64 + lq*16));
        acc2[ct] = __builtin_amdgcn_mfma_f32_16x16x32_bf16(akt[kk], bqt, acc2[ct], 0,0,0);
      }
    }
  }
  unsigned int a2p[8][2];
  {
    float m0=-1e30f, m1=-1e30f, m2=-1e30f, m3=-1e30f;
    #pragma unroll
    for (int t=0;t<8;t++){
      m0 = fmaxf(m0, acc2[t][0]); m1 = fmaxf(m1, acc2[t][1]);
      m2 = fmaxf(m2, acc2[t][2]); m3 = fmaxf(m3, acc2[t][3]);
    }
    #pragma unroll
    for (int d=1; d<16; d<<=1){
      m0 = fmaxf(m0, __shfl_xor(m0,d)); m1 = fmaxf(m1, __shfl_xor(m1,d));
      m2 = fmaxf(m2, __shfl_xor(m2,d)); m3 = fmaxf(m3, __shfl_xor(m3,d));
    }
    float s0=0.f, s1=0.f, s2=0.f, s3=0.f;
    #pragma unroll
    for (int t=0;t<8;t++){
      float e0 = __expf(acc2[t][0]-m0); acc2[t][0]=e0; s0 += e0;
      float e1 = __expf(acc2[t][1]-m1); acc2[t][1]=e1; s1 += e1;
      float e2 = __expf(acc2[t][2]-m2); acc2[t][2]=e2; s2 += e2;
      float e3 = __expf(acc2[t][3]-m3); acc2[t][3]=e3; s3 += e3;
    }
    #pragma unroll
    for (int d=1; d<16; d<<=1){
      s0 += __shfl_xor(s0,d); s1 += __shfl_xor(s1,d);
      s2 += __shfl_xor(s2,d); s3 += __shfl_xor(s3,d);
    }
    float i0=1.f/s0, i1=1.f/s1, i2=1.f/s2, i3=1.f/s3;
    #pragma unroll
    for (int t=0;t<8;t++){
      a2p[t][0] = pk2(acc2[t][0]*i0, acc2[t][1]*i1);
      a2p[t][1] = pk2(acc2[t][2]*i2, acc2[t][3]*i3);
    }
  }

  __syncthreads();

  // ---- write A1 -> B3 (rm), A2T -> B2 (rm), VT -> B1 ----
  {
    int r = 16*w + lm;
    #pragma unroll
    for (int t=0;t<8;t++)
      *(uint2*)(B3 + r*256 + swz(r, t*32 + lq*8)) = make_uint2(a1p[t][0], a1p[t][1]);
  }
  #pragma unroll
  for (int t=0;t<8;t++){
    int jr = t*16 + lm;
    *(uint2*)(B2 + jr*256 + swz(jr, 32*w + lq*8)) = make_uint2(a2p[t][0], a2p[t][1]);
  }
  #pragma unroll
  for (int i=0;i<4;i++){
    int e = (tid + 512*i)*8;
    int row = e>>7, col = e&127;
    unsigned int vd[4] = {vreg[i].x, vreg[i].y, vreg[i].z, vreg[i].w};
    #pragma unroll
    for (int u=0;u<8;u++){
      unsigned short ve = (unsigned short)(vd[u>>1] >> (16*(u&1)));
      int tr = col + u;
      *(unsigned short*)(B1 + tr*256 + swz(tr, row*2)) = ve;
    }
  }
  __syncthreads();

  // ---- P3: MT = V^T * A1^T ----
  f32x4 acc3[8];
  #pragma unroll
  for (int t=0;t<8;t++) acc3[t] = (f32x4){0.f,0.f,0.f,0.f};
  {
    bf16x8 av[4];
    #pragma unroll
    for (int kk=0;kk<4;kk++){
      int jr = 16*w + lm;
      av[kk] = *(const bf16x8*)(B1 + jr*256 + swz(jr, kk*64 + lq*16));
    }
    #pragma unroll
    for (int kk=0;kk<4;kk++){
      #pragma unroll
      for (int rt=0;rt<8;rt++){
        int rr = rt*16 + lm;
        bf16x8 ba = *(const bf16x8*)(B3 + rr*256 + swz(rr, kk*64 + lq*16));
        acc3[rt] = __builtin_amdgcn_mfma_f32_16x16x32_bf16(av[kk], ba, acc3[rt], 0,0,0);
      }
    }
  }
  #pragma unroll
  for (int rt=0;rt<8;rt++){
    int rr = rt*16 + lm;
    unsigned int p0 = pk2(acc3[rt][0], acc3[rt][1]);
    unsigned int p1 = pk2(acc3[rt][2], acc3[rt][3]);
    *(uint2*)(B0 + rr*256 + swz(rr, 32*w + lq*8)) = make_uint2(p0, p1);
  }
  __syncthreads();

  // ---- P4: P = M * A2 -> global bf16 ----
  f32x4 acc4[8];
  #pragma unroll
  for (int t=0;t<8;t++) acc4[t] = (f32x4){0.f,0.f,0.f,0.f};
  {
    bf16x8 am[4];
    #pragma unroll
    for (int kk=0;kk<4;kk++){
      int rr = 16*w + lm;
      am[kk] = *(const bf16x8*)(B0 + rr*256 + swz(rr, kk*64 + lq*16));
    }
    #pragma unroll
    for (int kk=0;kk<4;kk++){
      #pragma unroll
      for (int ct=0;ct<8;ct++){
        int jr = ct*16 + lm;
        bf16x8 ba2 = *(const bf16x8*)(B2 + jr*256 + swz(jr, kk*64 + lq*16));
        acc4[ct] = __builtin_amdgcn_mfma_f32_16x16x32_bf16(am[kk], ba2, acc4[ct], 0,0,0);
      }
    }
  }
  unsigned short* pout = Pb + gbase;
  #pragma unroll
  for (int ct=0;ct<8;ct++){
    #pragma unroll
    for (int r4=0;r4<4;r4++){
      int rr = 16*w + lq*4 + r4;
      pout[rr*HH + ct*16 + lm] = f2bf(acc4[ct][r4]);
    }
  }
}

// ---------------- Kernel 3: out = relu(conv1x1(P, w3, b3)) fp32, MFMA -----
// (r5-r9 version — verified fast)
__global__ __launch_bounds__(256, 6) void rc_conv_out(
    const unsigned short* __restrict__ Pb, const float* __restrict__ w3,
    const float* __restrict__ b3, float* __restrict__ out)
{
  __shared__ char Xs[16384];

  const int tid = threadIdx.x;
  const int b  = blockIdx.y;
  const int pblock = blockIdx.x * 128;
  const int w = tid>>6, l = tid&63, lq = l>>4, lm = l&15;
  const int orow = 16*w + lm;

  bf16x8 aW[2];
  {
    const float* wp = w3 + orow*64;
    float4 a0 = *(const float4*)(wp + lq*8);
    float4 a1 = *(const float4*)(wp + lq*8 + 4);
    float4 a2 = *(const float4*)(wp + 32 + lq*8);
    float4 a3 = *(const float4*)(wp + 32 + lq*8 + 4);
    aW[0] = pk8(a0, a1); aW[1] = pk8(a2, a3);
  }
  float4 bv4 = *(const float4*)(b3 + 16*w + 4*lq);
  const float* bv = (const float*)&bv4;

  const unsigned short* S = Pb + (size_t)b*NCH*NPOS + pblock;
  uint2 pr[2][4];
  #pragma unroll
  for (int g=0; g<2; ++g){
    int unit = tid + 256*g;
    int q  = unit >> 5;
    int p4 = (unit & 31) << 2;
    #pragma unroll
    for (int j=0;j<4;j++)
      pr[g][j] = *(const uint2*)(S + (size_t)(4*q+j)*NPOS + p4);
  }
  #pragma unroll
  for (int g=0; g<2; ++g){
    int unit = tid + 256*g;
    int q  = unit >> 5;
    int p4 = (unit & 31) << 2;
    const unsigned short* e0 = (const unsigned short*)&pr[g][0];
    const unsigned short* e1 = (const unsigned short*)&pr[g][1];
    const unsigned short* e2 = (const unsigned short*)&pr[g][2];
    const unsigned short* e3 = (const unsigned short*)&pr[g][3];
    #pragma unroll
    for (int u=0; u<4; ++u){
      uint2 pk;
      pk.x = (unsigned int)e0[u] | ((unsigned int)e1[u]<<16);
      pk.y = (unsigned int)e2[u] | ((unsigned int)e3[u]<<16);
      *(uint2*)(Xs + (p4+u)*128 + swz(p4+u, q*8)) = pk;
    }
  }
  __syncthreads();

  float* dst = out + (size_t)b*NCH*NPOS;
  #pragma unroll
  for (int pt=0; pt<8; ++pt){
    int prow = pt*16 + lm;
    bf16x8 bx0 = *(const bf16x8*)(Xs + prow*128 + swz(prow,      lq*16));
    bf16x8 bx1 = *(const bf16x8*)(Xs + prow*128 + swz(prow, 64 + lq*16));
    f32x4 acc = (f32x4){0.f,0.f,0.f,0.f};
    acc = __builtin_amdgcn_mfma_f32_16x16x32_bf16(aW[0], bx0, acc, 0,0,0);
    acc = __builtin_amdgcn_mfma_f32_16x16x32_bf16(aW[1], bx1, acc, 0,0,0);
    int p = pblock + pt*16 + lm;
    #pragma unroll
    for (int r4=0;r4<4;r4++){
      int o = 16*w + 4*lq + r4;
      dst[(size_t)o*NPOS + p] = fmaxf(acc[r4] + bv[r4], 0.f);
    }
  }
}

extern "C" void kernel_launch(void* const* d_in, const int* in_sizes, int n_in,
                              void* d_out, int out_size, void* d_ws, size_t ws_size,
                              hipStream_t stream)
{
  const float* x   = (const float*)d_in[0];
  const float* att = (const float*)d_in[1];
  const float* w0  = (const float*)d_in[2]; const float* b0 = (const float*)d_in[3];
  const float* w1  = (const float*)d_in[4]; const float* b1 = (const float*)d_in[5];
  const float* w2  = (const float*)d_in[6]; const float* b2 = (const float*)d_in[7];
  const float* w3  = (const float*)d_in[8]; const float* b3 = (const float*)d_in[9];

  const size_t NM = (size_t)NB*NCH*NPOS;          // 16,777,216 elems per matrix
  unsigned short* Qb = (unsigned short*)d_ws;     // bf16, 33.55 MB each
  unsigned short* Kb = Qb + NM;
  unsigned short* Vb = Kb + NM;
  unsigned short* Pb = Vb + NM;
  float* out = (float*)d_out;

  (void)hipFuncSetAttribute((const void*)rc_attention_mfma,
                            hipFuncAttributeMaxDynamicSharedMemorySize, 131072);

  rc_conv_in<<<dim3(128, NB, 2), 256, 0, stream>>>(x, att, w0,b0, w1,b1, w2,b2,
                                                   Qb, Kb, Vb);

  rc_attention_mfma<<<dim3(NB*NCH), 512, 131072, stream>>>(Qb, Kb, Vb, Pb);

  rc_conv_out<<<dim3(128, NB), 256, 0, stream>>>(Pb, w3, b3, out);
}

// Round 13
// 118.951 us; speedup vs baseline: 1.6461x; 1.1726x over previous
//
#include <hip/hip_runtime.h>
#include <stdint.h>

// Problem: B=16, C=64, H=W=128. fp32 in/out.
#define NB   16
#define NCH  64
#define HH   128
#define NPOS (HH*HH)        // 16384 spatial positions

typedef short bf16x8 __attribute__((ext_vector_type(8)));   // 8 bf16 = 4 VGPRs
typedef float f32x4  __attribute__((ext_vector_type(4)));

__device__ __forceinline__ unsigned short f2bf(float f){
  unsigned int u = __float_as_uint(f);
  u += 0x7FFFu + ((u>>16)&1u);          // RNE; inputs finite
  return (unsigned short)(u>>16);
}
__device__ __forceinline__ unsigned int pk2(float a, float b){
  return (unsigned int)f2bf(a) | ((unsigned int)f2bf(b)<<16);
}

// XOR swizzle on byte bits 4-6: spreads 16 consecutive rows over 8 16B slots
// (2 rows/slot = 2-way = free on b128 frag reads, m136).
__device__ __forceinline__ int swz(int row, int cb){
  return cb ^ (((row & 7) ^ ((row >> 3) & 7)) << 4);
}

// ---------------- Kernel 1: Q/V (m=0, from x) and K (m=1, from att) -------
// ROUND-4 VERSION (best timed config): MFMA conv1x1+ReLU -> bf16.
// 256 thr, 128-position tile. LDS: Xs 16KB + W LDS-staged (33.25KB total)
// -> 4 blocks/CU. All 8 staging loads in flight. Output via LDS bounce.
__global__ __launch_bounds__(256, 4) void rc_conv_in(
    const float* __restrict__ x, const float* __restrict__ att,
    const float* __restrict__ w0, const float* __restrict__ b0,
    const float* __restrict__ w1, const float* __restrict__ b1,
    const float* __restrict__ w2, const float* __restrict__ b2,
    unsigned short* __restrict__ Qb, unsigned short* __restrict__ Kb,
    unsigned short* __restrict__ Vb)
{
  __shared__ char smem[33280];
  char* Xs  = smem;                    // 128 p-rows x 128 B (bounce: 64 x 256 B)
  char* WsA = smem + 16384;            // 64 o-rows x 128 B
  char* WsB = smem + 24576;
  float* biasA = (float*)(smem + 32768);
  float* biasB = (float*)(smem + 33024);

  const int tid = threadIdx.x;
  const int m  = blockIdx.z;
  const int b  = blockIdx.y;
  const int pblock = blockIdx.x * 128;
  const float* src = m ? att : x;
  const float* wA  = m ? w1 : w0;
  const float* bA  = m ? b1 : b0;

  // ---- stage W(s) as bf16, swizzled rows ----
  {
    int o = tid >> 2, c0 = (tid & 3) * 16;
    const float4* wr = (const float4*)(wA + o*64 + c0);
    float4 f0 = wr[0], f1 = wr[1], f2v = wr[2], f3 = wr[3];
    uint4 pa, pb;
    pa.x = pk2(f0.x,f0.y);  pa.y = pk2(f0.z,f0.w);
    pa.z = pk2(f1.x,f1.y);  pa.w = pk2(f1.z,f1.w);
    pb.x = pk2(f2v.x,f2v.y); pb.y = pk2(f2v.z,f2v.w);
    pb.z = pk2(f3.x,f3.y);  pb.w = pk2(f3.z,f3.w);
    *(uint4*)(WsA + o*128 + swz(o, c0*2))      = pa;
    *(uint4*)(WsA + o*128 + swz(o, c0*2 + 16)) = pb;
    if (m == 0){
      const float4* wr2 = (const float4*)(w2 + o*64 + c0);
      float4 g0 = wr2[0], g1 = wr2[1], g2 = wr2[2], g3 = wr2[3];
      uint4 qa, qb;
      qa.x = pk2(g0.x,g0.y); qa.y = pk2(g0.z,g0.w);
      qa.z = pk2(g1.x,g1.y); qa.w = pk2(g1.z,g1.w);
      qb.x = pk2(g2.x,g2.y); qb.y = pk2(g2.z,g2.w);
      qb.z = pk2(g3.x,g3.y); qb.w = pk2(g3.z,g3.w);
      *(uint4*)(WsB + o*128 + swz(o, c0*2))      = qa;
      *(uint4*)(WsB + o*128 + swz(o, c0*2 + 16)) = qb;
    }
  }
  if (tid < 64){
    biasA[tid] = bA[tid];
    if (m == 0) biasB[tid] = b2[tid];
  }

  // ---- stage X tile: ALL 8 loads issued, then transpose-pack to LDS ----
  const float* S = src + (size_t)b*NCH*NPOS + pblock;
  float4 xr[2][4];
  #pragma unroll
  for (int g=0; g<2; ++g){
    int unit = tid + 256*g;           // 0..511 = 16 cquads x 32 pgroups
    int q  = unit >> 5;               // channel quad 0..15
    int p4 = (unit & 31) << 2;        // position 0..127 step 4
    #pragma unroll
    for (int j=0;j<4;j++)
      xr[g][j] = *(const float4*)(S + (size_t)(4*q+j)*NPOS + p4);
  }
  #pragma unroll
  for (int g=0; g<2; ++g){
    int unit = tid + 256*g;
    int q  = unit >> 5;
    int p4 = (unit & 31) << 2;
    const float* c0 = (const float*)&xr[g][0];
    const float* c1 = (const float*)&xr[g][1];
    const float* c2 = (const float*)&xr[g][2];
    const float* c3 = (const float*)&xr[g][3];
    #pragma unroll
    for (int u=0; u<4; ++u){
      uint2 pk;
      pk.x = pk2(c0[u], c1[u]);
      pk.y = pk2(c2[u], c3[u]);
      *(uint2*)(Xs + (p4+u)*128 + swz(p4+u, q*8)) = pk;
    }
  }
  __syncthreads();

  // ---- MFMA: D[o',p'] = sum_c W[o,c]*X[p,c] ----
  const int w = tid>>6, l = tid&63, lq = l>>4, lm = l&15;
  bf16x8 aQ[2], aV[2] = {};
  {
    int orow = 16*w + lm;
    aQ[0] = *(const bf16x8*)(WsA + orow*128 + swz(orow,      lq*16));
    aQ[1] = *(const bf16x8*)(WsA + orow*128 + swz(orow, 64 + lq*16));
    if (m == 0){
      aV[0] = *(const bf16x8*)(WsB + orow*128 + swz(orow,      lq*16));
      aV[1] = *(const bf16x8*)(WsB + orow*128 + swz(orow, 64 + lq*16));
    }
  }
  float bQv[4], bVv[4];
  #pragma unroll
  for (int r4=0;r4<4;r4++){
    int o = 16*w + 4*lq + r4;
    bQv[r4] = biasA[o];
    bVv[r4] = (m==0) ? biasB[o] : 0.f;
  }

  f32x4 accQ[8], accV[8];
  #pragma unroll
  for (int pt=0;pt<8;pt++){ accQ[pt]=(f32x4){0,0,0,0}; accV[pt]=(f32x4){0,0,0,0}; }
  #pragma unroll
  for (int pt=0; pt<8; ++pt){
    int prow = pt*16 + lm;
    bf16x8 bx0 = *(const bf16x8*)(Xs + prow*128 + swz(prow,      lq*16));
    bf16x8 bx1 = *(const bf16x8*)(Xs + prow*128 + swz(prow, 64 + lq*16));
    accQ[pt] = __builtin_amdgcn_mfma_f32_16x16x32_bf16(aQ[0], bx0, accQ[pt], 0,0,0);
    accQ[pt] = __builtin_amdgcn_mfma_f32_16x16x32_bf16(aQ[1], bx1, accQ[pt], 0,0,0);
    if (m == 0){
      accV[pt] = __builtin_amdgcn_mfma_f32_16x16x32_bf16(aV[0], bx0, accV[pt], 0,0,0);
      accV[pt] = __builtin_amdgcn_mfma_f32_16x16x32_bf16(aV[1], bx1, accV[pt], 0,0,0);
    }
  }

  // ---- bounce + coalesced store (Xs reused as 64 o-rows x 256 B) ----
  unsigned short* dA = (m ? Kb : Qb) + (size_t)b*NCH*NPOS;
  unsigned short* dB = Vb + (size_t)b*NCH*NPOS;
  const int skw = 32*((4*w + lq) & 7);     // = 32*((o>>2)&7) for this quarter

  __syncthreads();                          // all MFMA frag reads of Xs done
  #pragma unroll
  for (int pt=0; pt<8; ++pt){
    #pragma unroll
    for (int r4=0;r4<4;r4++){
      int o = 16*w + 4*lq + r4;
      int p = pt*16 + lm;
      *(unsigned short*)(Xs + o*256 + ((2*p + skw) & 255)) =
          f2bf(fmaxf(accQ[pt][r4] + bQv[r4], 0.f));
    }
  }
  __syncthreads();
  {
    int o = tid >> 2, jj = tid & 3;
    int sk2 = 32*((o>>2)&7);
    #pragma unroll
    for (int i=0;i<4;i++){
      int j = i*4 + jj;                    // 16B chunk index in row
      uint4 v = *(const uint4*)(Xs + o*256 + ((j*16 + sk2) & 255));
      *(uint4*)(dA + (size_t)o*NPOS + pblock + j*8) = v;
    }
  }
  if (m == 0){
    __syncthreads();                        // store-reads done before overwrite
    #pragma unroll
    for (int pt=0; pt<8; ++pt){
      #pragma unroll
      for (int r4=0;r4<4;r4++){
        int o = 16*w + 4*lq + r4;
        int p = pt*16 + lm;
        *(unsigned short*)(Xs + o*256 + ((2*p + skw) & 255)) =
            f2bf(fmaxf(accV[pt][r4] + bVv[r4], 0.f));
      }
    }
    __syncthreads();
    int o = tid >> 2, jj = tid & 3;
    int sk2 = 32*((o>>2)&7);
    #pragma unroll
    for (int i=0;i<4;i++){
      int j = i*4 + jj;
      uint4 v = *(const uint4*)(Xs + o*256 + ((j*16 + sk2) & 255));
      *(uint4*)(dB + (size_t)o*NPOS + pblock + j*8) = v;
    }
  }
}

// ---------------- Kernel 2: fused per-(b,c) MFMA attention ----------------
// ROUND-4 VERIFIED VERSION (78 µs profiled, VGPR 112): 1024 blocks x 512
// threads (8 waves), 4 x 32KB buffers (131KB LDS, 1 block/CU). Single
// staging phase (Q,K rm + transposed together) -> P1,P2 back-to-back.
__global__ __launch_bounds__(512) void rc_attention_mfma(
    const unsigned short* __restrict__ Qb, const unsigned short* __restrict__ Kb,
    const unsigned short* __restrict__ Vb, unsigned short* __restrict__ Pb)
{
  extern __shared__ char lds[];
  char* B0 = lds;
  char* B1 = lds + 32768;
  char* B2 = lds + 65536;
  char* B3 = lds + 98304;
  const int tid = threadIdx.x;
  const int l  = tid & 63;
  const int w  = tid >> 6;          // wave 0..7
  const int lq = l >> 4;            // quarter 0..3
  const int lm = l & 15;
  const size_t gbase = (size_t)blockIdx.x * NPOS;

  // ---- V global loads early (held in regs through P1/P2) ----
  uint4 vreg[4];
  #pragma unroll
  for (int i=0;i<4;i++)
    vreg[i] = *(const uint4*)(Vb + gbase + (size_t)(tid + 512*i)*8);

  // ---- stage Q,K row-major + transposed ----
  #pragma unroll
  for (int i=0;i<4;i++){
    int e = (tid + 512*i)*8;
    int row = e >> 7, col = e & 127;
    uint4 q = *(const uint4*)(Qb + gbase + e);
    uint4 k = *(const uint4*)(Kb + gbase + e);
    *(uint4*)(B0 + row*256 + swz(row, col*2)) = q;
    *(uint4*)(B1 + row*256 + swz(row, col*2)) = k;
    unsigned int qd[4] = {q.x,q.y,q.z,q.w};
    unsigned int kd[4] = {k.x,k.y,k.z,k.w};
    #pragma unroll
    for (int u=0;u<8;u++){
      unsigned short qe = (unsigned short)(qd[u>>1] >> (16*(u&1)));
      unsigned short ke = (unsigned short)(kd[u>>1] >> (16*(u&1)));
      int tr = col + u;             // T-row = original col
      *(unsigned short*)(B2 + tr*256 + swz(tr, row*2)) = qe;
      *(unsigned short*)(B3 + tr*256 + swz(tr, row*2)) = ke;
    }
  }
  __syncthreads();

  // ---- P1: S1T = K * Q^T ----
  f32x4 acc1[8];
  #pragma unroll
  for (int t=0;t<8;t++) acc1[t] = (f32x4){0.f,0.f,0.f,0.f};
  {
    bf16x8 bq[4];
    #pragma unroll
    for (int kk=0;kk<4;kk++){
      int r = 16*w + lm;
      bq[kk] = *(const bf16x8*)(B0 + r*256 + swz(r, kk*64 + lq*16));
    }
    #pragma unroll
    for (int kk=0;kk<4;kk++){
      #pragma unroll
      for (int jt=0;jt<8;jt++){
        int jr = jt*16 + lm;
        bf16x8 ak = *(const bf16x8*)(B1 + jr*256 + swz(jr, kk*64 + lq*16));
        acc1[jt] = __builtin_amdgcn_mfma_f32_16x16x32_bf16(ak, bq[kk], acc1[jt], 0,0,0);
      }
    }
  }
  unsigned int a1p[8][2];
  {
    float mx = -1e30f;
    #pragma unroll
    for (int t=0;t<8;t++)
      mx = fmaxf(mx, fmaxf(fmaxf(acc1[t][0], acc1[t][1]), fmaxf(acc1[t][2], acc1[t][3])));
    mx = fmaxf(mx, __shfl_xor(mx, 16));
    mx = fmaxf(mx, __shfl_xor(mx, 32));
    float sum = 0.f;
    #pragma unroll
    for (int t=0;t<8;t++){
      #pragma unroll
      for (int r4=0;r4<4;r4++){ float e = __expf(acc1[t][r4] - mx); acc1[t][r4] = e; sum += e; }
    }
    sum += __shfl_xor(sum, 16);
    sum += __shfl_xor(sum, 32);
    float inv = 1.f/sum;
    #pragma unroll
    for (int t=0;t<8;t++){
      a1p[t][0] = pk2(acc1[t][0]*inv, acc1[t][1]*inv);
      a1p[t][1] = pk2(acc1[t][2]*inv, acc1[t][3]*inv);
    }
  }

  // ---- P2: S2 = K^T * Q ----
  f32x4 acc2[8];
  #pragma unroll
  for (int t=0;t<8;t++) acc2[t] = (f32x4){0.f,0.f,0.f,0.f};
  {
    bf16x8 akt[4];
    #pragma unroll
    for (int kk=0;kk<4;kk++){
      int ir = 16*w + lm;
      akt[kk] = *(const bf16x8*)(B3 + ir*256 + swz(ir, kk*64 + lq*16));
    }
    #pragma unroll
    for (int kk=0;kk<4;kk++){
      #pragma unroll
      for (int ct=0;ct<8;ct++){
        int jr = ct*16 + lm;
        bf16x8 bqt = *(const bf16x8*)(B2 + jr*256 + swz(jr, kk*64 + lq*16));
        acc2[ct] = __builtin_amdgcn_mfma_f32_16x16x32_bf16(akt[kk], bqt, acc2[ct], 0,0,0);
      }
    }
  }
  unsigned int a2p[8][2];
  {
    float m0=-1e30f, m1=-1e30f, m2=-1e30f, m3=-1e30f;
    #pragma unroll
    for (int t=0;t<8;t++){
      m0 = fmaxf(m0, acc2[t][0]); m1 = fmaxf(m1, acc2[t][1]);
      m2 = fmaxf(m2, acc2[t][2]); m3 = fmaxf(m3, acc2[t][3]);
    }
    #pragma unroll
    for (int d=1; d<16; d<<=1){
      m0 = fmaxf(m0, __shfl_xor(m0,d)); m1 = fmaxf(m1, __shfl_xor(m1,d));
      m2 = fmaxf(m2, __shfl_xor(m2,d)); m3 = fmaxf(m3, __shfl_xor(m3,d));
    }
    float s0=0.f, s1=0.f, s2=0.f, s3=0.f;
    #pragma unroll
    for (int t=0;t<8;t++){
      float e0 = __expf(acc2[t][0]-m0); acc2[t][0]=e0; s0 += e0;
      float e1 = __expf(acc2[t][1]-m1); acc2[t][1]=e1; s1 += e1;
      float e2 = __expf(acc2[t][2]-m2); acc2[t][2]=e2; s2 += e2;
      float e3 = __expf(acc2[t][3]-m3); acc2[t][3]=e3; s3 += e3;
    }
    #pragma unroll
    for (int d=1; d<16; d<<=1){
      s0 += __shfl_xor(s0,d); s1 += __shfl_xor(s1,d);
      s2 += __shfl_xor(s2,d); s3 += __shfl_xor(s3,d);
    }
    float i0=1.f/s0, i1=1.f/s1, i2=1.f/s2, i3=1.f/s3;
    #pragma unroll
    for (int t=0;t<8;t++){
      a2p[t][0] = pk2(acc2[t][0]*i0, acc2[t][1]*i1);
      a2p[t][1] = pk2(acc2[t][2]*i2, acc2[t][3]*i3);
    }
  }

  __syncthreads();

  // ---- write A1 -> B3 (rm), A2T -> B2 (rm), VT -> B1 ----
  {
    int r = 16*w + lm;
    #pragma unroll
    for (int t=0;t<8;t++)
      *(uint2*)(B3 + r*256 + swz(r, t*32 + lq*8)) = make_uint2(a1p[t][0], a1p[t][1]);
  }
  #pragma unroll
  for (int t=0;t<8;t++){
    int jr = t*16 + lm;
    *(uint2*)(B2 + jr*256 + swz(jr, 32*w + lq*8)) = make_uint2(a2p[t][0], a2p[t][1]);
  }
  #pragma unroll
  for (int i=0;i<4;i++){
    int e = (tid + 512*i)*8;
    int row = e>>7, col = e&127;
    unsigned int vd[4] = {vreg[i].x, vreg[i].y, vreg[i].z, vreg[i].w};
    #pragma unroll
    for (int u=0;u<8;u++){
      unsigned short ve = (unsigned short)(vd[u>>1] >> (16*(u&1)));
      int tr = col + u;
      *(unsigned short*)(B1 + tr*256 + swz(tr, row*2)) = ve;
    }
  }
  __syncthreads();

  // ---- P3: MT = V^T * A1^T ----
  f32x4 acc3[8];
  #pragma unroll
  for (int t=0;t<8;t++) acc3[t] = (f32x4){0.f,0.f,0.f,0.f};
  {
    bf16x8 av[4];
    #pragma unroll
    for (int kk=0;kk<4;kk++){
      int jr = 16*w + lm;
      av[kk] = *(const bf16x8*)(B1 + jr*256 + swz(jr, kk*64 + lq*16));
    }
    #pragma unroll
    for (int kk=0;kk<4;kk++){
      #pragma unroll
      for (int rt=0;rt<8;rt++){
        int rr = rt*16 + lm;
        bf16x8 ba = *(const bf16x8*)(B3 + rr*256 + swz(rr, kk*64 + lq*16));
        acc3[rt] = __builtin_amdgcn_mfma_f32_16x16x32_bf16(av[kk], ba, acc3[rt], 0,0,0);
      }
    }
  }
  #pragma unroll
  for (int rt=0;rt<8;rt++){
    int rr = rt*16 + lm;
    unsigned int p0 = pk2(acc3[rt][0], acc3[rt][1]);
    unsigned int p1 = pk2(acc3[rt][2], acc3[rt][3]);
    *(uint2*)(B0 + rr*256 + swz(rr, 32*w + lq*8)) = make_uint2(p0, p1);
  }
  __syncthreads();

  // ---- P4: P = M * A2 -> global bf16 ----
  f32x4 acc4[8];
  #pragma unroll
  for (int t=0;t<8;t++) acc4[t] = (f32x4){0.f,0.f,0.f,0.f};
  {
    bf16x8 am[4];
    #pragma unroll
    for (int kk=0;kk<4;kk++){
      int rr = 16*w + lm;
      am[kk] = *(const bf16x8*)(B0 + rr*256 + swz(rr, kk*64 + lq*16));
    }
    #pragma unroll
    for (int kk=0;kk<4;kk++){
      #pragma unroll
      for (int ct=0;ct<8;ct++){
        int jr = ct*16 + lm;
        bf16x8 ba2 = *(const bf16x8*)(B2 + jr*256 + swz(jr, kk*64 + lq*16));
        acc4[ct] = __builtin_amdgcn_mfma_f32_16x16x32_bf16(am[kk], ba2, acc4[ct], 0,0,0);
      }
    }
  }
  unsigned short* pout = Pb + gbase;
  #pragma unroll
  for (int ct=0;ct<8;ct++){
    #pragma unroll
    for (int r4=0;r4<4;r4++){
      int rr = 16*w + lq*4 + r4;
      pout[rr*HH + ct*16 + lm] = f2bf(acc4[ct][r4]);
    }
  }
}

// ---------------- Kernel 3: out = relu(conv1x1(P, w3, b3)) fp32, MFMA -----
// ROUND-4 VERSION: 128-position tile, 25KB LDS (W3 staged) -> 6 blocks/CU.
__global__ __launch_bounds__(256, 6) void rc_conv_out(
    const unsigned short* __restrict__ Pb, const float* __restrict__ w3,
    const float* __restrict__ b3, float* __restrict__ out)
{
  __shared__ char smem[24832];
  char* Xs = smem;                     // 128 p-rows x 128 B
  char* Ws = smem + 16384;             // 64 o-rows x 128 B
  float* bias = (float*)(smem + 24576);

  const int tid = threadIdx.x;
  const int b  = blockIdx.y;
  const int pblock = blockIdx.x * 128;

  {
    int o = tid >> 2, c0 = (tid & 3) * 16;
    const float4* wr = (const float4*)(w3 + o*64 + c0);
    float4 f0 = wr[0], f1 = wr[1], f2v = wr[2], f3 = wr[3];
    uint4 pa, pb;
    pa.x = pk2(f0.x,f0.y);  pa.y = pk2(f0.z,f0.w);
    pa.z = pk2(f1.x,f1.y);  pa.w = pk2(f1.z,f1.w);
    pb.x = pk2(f2v.x,f2v.y); pb.y = pk2(f2v.z,f2v.w);
    pb.z = pk2(f3.x,f3.y);  pb.w = pk2(f3.z,f3.w);
    *(uint4*)(Ws + o*128 + swz(o, c0*2))      = pa;
    *(uint4*)(Ws + o*128 + swz(o, c0*2 + 16)) = pb;
  }
  if (tid < 64) bias[tid] = b3[tid];

  // ---- stage P tile: all 8 loads in flight, then pack to LDS ----
  const unsigned short* S = Pb + (size_t)b*NCH*NPOS + pblock;
  uint2 pr[2][4];
  #pragma unroll
  for (int g=0; g<2; ++g){
    int unit = tid + 256*g;
    int q  = unit >> 5;
    int p4 = (unit & 31) << 2;
    #pragma unroll
    for (int j=0;j<4;j++)
      pr[g][j] = *(const uint2*)(S + (size_t)(4*q+j)*NPOS + p4);
  }
  #pragma unroll
  for (int g=0; g<2; ++g){
    int unit = tid + 256*g;
    int q  = unit >> 5;
    int p4 = (unit & 31) << 2;
    const unsigned short* e0 = (const unsigned short*)&pr[g][0];
    const unsigned short* e1 = (const unsigned short*)&pr[g][1];
    const unsigned short* e2 = (const unsigned short*)&pr[g][2];
    const unsigned short* e3 = (const unsigned short*)&pr[g][3];
    #pragma unroll
    for (int u=0; u<4; ++u){
      uint2 pk;
      pk.x = (unsigned int)e0[u] | ((unsigned int)e1[u]<<16);
      pk.y = (unsigned int)e2[u] | ((unsigned int)e3[u]<<16);
      *(uint2*)(Xs + (p4+u)*128 + swz(p4+u, q*8)) = pk;
    }
  }
  __syncthreads();

  const int w = tid>>6, l = tid&63, lq = l>>4, lm = l&15;
  bf16x8 aW[2];
  {
    int orow = 16*w + lm;
    aW[0] = *(const bf16x8*)(Ws + orow*128 + swz(orow,      lq*16));
    aW[1] = *(const bf16x8*)(Ws + orow*128 + swz(orow, 64 + lq*16));
  }
  float bv[4];
  #pragma unroll
  for (int r4=0;r4<4;r4++) bv[r4] = bias[16*w + 4*lq + r4];

  float* dst = out + (size_t)b*NCH*NPOS;
  #pragma unroll
  for (int pt=0; pt<8; ++pt){
    int prow = pt*16 + lm;
    bf16x8 bx0 = *(const bf16x8*)(Xs + prow*128 + swz(prow,      lq*16));
    bf16x8 bx1 = *(const bf16x8*)(Xs + prow*128 + swz(prow, 64 + lq*16));
    f32x4 acc = (f32x4){0.f,0.f,0.f,0.f};
    acc = __builtin_amdgcn_mfma_f32_16x16x32_bf16(aW[0], bx0, acc, 0,0,0);
    acc = __builtin_amdgcn_mfma_f32_16x16x32_bf16(aW[1], bx1, acc, 0,0,0);
    int p = pblock + pt*16 + lm;
    #pragma unroll
    for (int r4=0;r4<4;r4++){
      int o = 16*w + 4*lq + r4;
      dst[(size_t)o*NPOS + p] = fmaxf(acc[r4] + bv[r4], 0.f);
    }
  }
}

extern "C" void kernel_launch(void* const* d_in, const int* in_sizes, int n_in,
                              void* d_out, int out_size, void* d_ws, size_t ws_size,
                              hipStream_t stream)
{
  const float* x   = (const float*)d_in[0];
  const float* att = (const float*)d_in[1];
  const float* w0  = (const float*)d_in[2]; const float* b0 = (const float*)d_in[3];
  const float* w1  = (const float*)d_in[4]; const float* b1 = (const float*)d_in[5];
  const float* w2  = (const float*)d_in[6]; const float* b2 = (const float*)d_in[7];
  const float* w3  = (const float*)d_in[8]; const float* b3 = (const float*)d_in[9];

  const size_t NM = (size_t)NB*NCH*NPOS;          // 16,777,216 elems per matrix
  unsigned short* Qb = (unsigned short*)d_ws;     // bf16, 33.55 MB each
  unsigned short* Kb = Qb + NM;
  unsigned short* Vb = Kb + NM;
  unsigned short* Pb = Vb + NM;
  float* out = (float*)d_out;

  (void)hipFuncSetAttribute((const void*)rc_attention_mfma,
                            hipFuncAttributeMaxDynamicSharedMemorySize, 131072);

  rc_conv_in<<<dim3(128, NB, 2), 256, 0, stream>>>(x, att, w0,b0, w1,b1, w2,b2,
                                                   Qb, Kb, Vb);

  rc_attention_mfma<<<dim3(NB*NCH), 512, 131072, stream>>>(Qb, Kb, Vb, Pb);

  rc_conv_out<<<dim3(128, NB), 256, 0, stream>>>(Pb, w3, b3, out);
}